// Round 8
// baseline (527.620 us; speedup 1.0000x reference)
//
#include <hip/hip_runtime.h>
#include <stdint.h>

constexpr int B_     = 128;
constexpr int S_     = 400;
constexpr int EMB_   = 128;
constexpr int ENC_   = 1024;
constexpr int DEC_   = 300;
constexpr int VOCAB_ = 50000;
constexpr int OOV_   = 50;
constexpr int OUTW_  = VOCAB_ + OOV_;   // 50050
constexpr int KHW_   = ENC_ + DEC_;     // 1324
constexpr int KHWP_  = 1344;            // 7*192, zero-padded K for MFMA
constexpr int G3_    = 3 * DEC_;        // 900
constexpr int KIN_   = EMB_ + ENC_;     // 1152
constexpr int CHK_   = 192;             // K-chunk staged in LDS (outproj)
constexpr int ALDS_STRIDE_ = 200;       // bf16 elems; 400B row stride
constexpr int PSTRIDE_ = 1028;          // flash partial: 1024 wa + m + l (+pad)
constexpr int NTILE_ = 782;             // outproj col tiles (64 each)

typedef __attribute__((ext_vector_type(4))) float f32x4;
typedef __attribute__((ext_vector_type(8))) short short8;

__device__ __forceinline__ float dot4(float4 a, float4 b) {
  return a.x * b.x + a.y * b.y + a.z * b.z + a.w * b.w;
}

__device__ __forceinline__ short f2bf(float f) {  // RNE f32 -> bf16
  uint32_t u = __builtin_bit_cast(uint32_t, f);
  u += 0x7fffu + ((u >> 16) & 1u);
  return (short)(u >> 16);
}

// v[b,e] = sum_d W[e,d] * h[b,d]
__global__ __launch_bounds__(256) void k_compute_v(const float* __restrict__ W,
                                                   const float* __restrict__ h,
                                                   float* __restrict__ v) {
  int b = blockIdx.x;
  __shared__ __align__(16) float hs[DEC_];
  for (int d = threadIdx.x; d < DEC_; d += 256) hs[d] = h[b * DEC_ + d];
  __syncthreads();
  for (int e = threadIdx.x; e < ENC_; e += 256) {
    const float4* w4 = (const float4*)(W + (size_t)e * DEC_);
    const float4* h4 = (const float4*)hs;
    float acc = 0.f;
    #pragma unroll 5
    for (int d = 0; d < DEC_ / 4; ++d) acc += dot4(w4[d], h4[d]);
    v[b * ENC_ + e] = acc;
  }
}

// Flash pass, 2-row ILP: scores + online softmax-weighted enc sum; per-wave partials.
__global__ __launch_bounds__(256) void k_attn_pass(const float* __restrict__ enc,
                                                   const float* __restrict__ v,
                                                   float* __restrict__ scores,
                                                   float* __restrict__ part, int nsplit) {
  int b = blockIdx.x, split = blockIdx.y;
  int wave = threadIdx.x >> 6, lane = threadIdx.x & 63;
  float4 vr[4];
  #pragma unroll
  for (int c = 0; c < 4; ++c) vr[c] = *(const float4*)(v + b * ENC_ + c * 256 + lane * 4);
  float m = -INFINITY, l = 0.f;
  float4 wa[4];
  #pragma unroll
  for (int c = 0; c < 4; ++c) wa[c] = make_float4(0.f, 0.f, 0.f, 0.f);
  int rows = S_ / nsplit, s0 = split * rows, s_end = s0 + rows;
  int s = s0 + wave;
  for (; s + 4 < s_end; s += 8) {
    const float* era = enc + ((size_t)b * S_ + s) * ENC_;
    const float* erb = enc + ((size_t)b * S_ + s + 4) * ENC_;
    float4 e4a[4], e4b[4];
    #pragma unroll
    for (int c = 0; c < 4; ++c) {
      e4a[c] = *(const float4*)(era + c * 256 + lane * 4);
      e4b[c] = *(const float4*)(erb + c * 256 + lane * 4);
    }
    float pa = 0.f, pb = 0.f;
    #pragma unroll
    for (int c = 0; c < 4; ++c) { pa += dot4(e4a[c], vr[c]); pb += dot4(e4b[c], vr[c]); }
    #pragma unroll
    for (int off = 32; off; off >>= 1) {
      pa += __shfl_xor(pa, off);
      pb += __shfl_xor(pb, off);
    }
    if (lane == 0) { scores[b * S_ + s] = pa; scores[b * S_ + s + 4] = pb; }
    float nm = fmaxf(m, fmaxf(pa, pb));
    float sc = __expf(m - nm);
    float ea = __expf(pa - nm);
    float eb = __expf(pb - nm);
    l = l * sc + ea + eb;
    #pragma unroll
    for (int c = 0; c < 4; ++c) {
      wa[c].x = wa[c].x * sc + ea * e4a[c].x + eb * e4b[c].x;
      wa[c].y = wa[c].y * sc + ea * e4a[c].y + eb * e4b[c].y;
      wa[c].z = wa[c].z * sc + ea * e4a[c].z + eb * e4b[c].z;
      wa[c].w = wa[c].w * sc + ea * e4a[c].w + eb * e4b[c].w;
    }
    m = nm;
  }
  if (s < s_end) {  // tail single row
    const float* er = enc + ((size_t)b * S_ + s) * ENC_;
    float4 e4[4];
    #pragma unroll
    for (int c = 0; c < 4; ++c) e4[c] = *(const float4*)(er + c * 256 + lane * 4);
    float p = 0.f;
    #pragma unroll
    for (int c = 0; c < 4; ++c) p += dot4(e4[c], vr[c]);
    #pragma unroll
    for (int off = 32; off; off >>= 1) p += __shfl_xor(p, off);
    if (lane == 0) scores[b * S_ + s] = p;
    float nm = fmaxf(m, p);
    float sc = __expf(m - nm), pe = __expf(p - nm);
    l = l * sc + pe;
    #pragma unroll
    for (int c = 0; c < 4; ++c) {
      wa[c].x = wa[c].x * sc + pe * e4[c].x;
      wa[c].y = wa[c].y * sc + pe * e4[c].y;
      wa[c].z = wa[c].z * sc + pe * e4[c].z;
      wa[c].w = wa[c].w * sc + pe * e4[c].w;
    }
    m = nm;
  }
  float* pp = part + ((size_t)b * (nsplit * 4) + split * 4 + wave) * PSTRIDE_;
  #pragma unroll
  for (int c = 0; c < 4; ++c) *(float4*)(pp + c * 256 + lane * 4) = wa[c];
  if (lane == 0) { pp[1024] = m; pp[1025] = l; }
}

// Merge partials -> w1[b,:] (f32) for GRU input
__global__ __launch_bounds__(256) void k_attn_merge1(const float* __restrict__ part, int P,
                                                     float* __restrict__ wout) {
  int b = blockIdx.x, tid = threadIdx.x;
  const float* pb = part + (size_t)b * P * PSTRIDE_;
  __shared__ float scl[32];
  __shared__ float Ls;
  if (tid == 0) {
    float M = -INFINITY;
    for (int p = 0; p < P; ++p) M = fmaxf(M, pb[p * PSTRIDE_ + 1024]);
    float L = 0.f;
    for (int p = 0; p < P; ++p) {
      float lp = pb[p * PSTRIDE_ + 1025];
      float e = (lp > 0.f) ? __expf(pb[p * PSTRIDE_ + 1024] - M) : 0.f;
      scl[p] = e;
      L += lp * e;
    }
    Ls = L;
  }
  __syncthreads();
  float invL = 1.f / Ls;
  for (int e = tid; e < ENC_; e += 256) {
    float acc = 0.f;
    for (int p = 0; p < P; ++p) acc += scl[p] * pb[p * PSTRIDE_ + e];
    wout[(size_t)b * ENC_ + e] = acc * invL;
  }
}

// Merge partials (attn2) -> hwb bf16 [b,300:1324], ml2, and finish p_gen.
__global__ __launch_bounds__(256) void k_attn_merge2(const float* __restrict__ part, int P,
                                                     short* __restrict__ hwb,
                                                     float* __restrict__ ml,
                                                     const float* __restrict__ W_p,
                                                     const float* __restrict__ b_p,
                                                     const float* __restrict__ pg_acc,
                                                     float* __restrict__ pg) {
  int b = blockIdx.x, tid = threadIdx.x;
  const float* pb = part + (size_t)b * P * PSTRIDE_;
  __shared__ float scl[32];
  __shared__ float Ls;
  __shared__ float red[256];
  if (tid == 0) {
    float M = -INFINITY;
    for (int p = 0; p < P; ++p) M = fmaxf(M, pb[p * PSTRIDE_ + 1024]);
    float L = 0.f;
    for (int p = 0; p < P; ++p) {
      float lp = pb[p * PSTRIDE_ + 1025];
      float e = (lp > 0.f) ? __expf(pb[p * PSTRIDE_ + 1024] - M) : 0.f;
      scl[p] = e;
      L += lp * e;
    }
    Ls = L;
    ml[b * 2] = M; ml[b * 2 + 1] = L;
  }
  __syncthreads();
  float invL = 1.f / Ls;
  float pacc = 0.f;
  for (int e = tid; e < ENC_; e += 256) {
    float acc = 0.f;
    for (int p = 0; p < P; ++p) acc += scl[p] * pb[p * PSTRIDE_ + e];
    float w = acc * invL;
    hwb[(size_t)b * KHWP_ + DEC_ + e] = f2bf(w);
    pacc += w * W_p[DEC_ + e];
  }
  if (tid < KHWP_ - KHW_) hwb[(size_t)b * KHWP_ + KHW_ + tid] = 0;  // zero pad
  red[tid] = pacc;
  __syncthreads();
  for (int st = 128; st > 0; st >>= 1) {
    if (tid < st) red[tid] += red[tid + st];
    __syncthreads();
  }
  if (tid == 0) pg[b] = 1.f / (1.f + __expf(-(red[0] + pg_acc[b] + b_p[0])));
}

// GRU gate pre-activations: gx[g,b], gh[g,b]; also zeroes pg_acc.
__global__ __launch_bounds__(256) void k_gates(const float* __restrict__ emb,
                                               const float* __restrict__ wgt,
                                               const float* __restrict__ h1,
                                               const float* __restrict__ W_ih,
                                               const float* __restrict__ W_hh,
                                               const float* __restrict__ b_ih,
                                               const float* __restrict__ b_hh,
                                               float* __restrict__ gx, float* __restrict__ gh,
                                               float* __restrict__ pg_acc) {
  int idx = blockIdx.x * 256 + threadIdx.x;
  if (idx < B_) pg_acc[idx] = 0.f;
  int b = idx & (B_ - 1);
  int g = idx >> 7;
  if (g >= G3_) return;
  const float4* wr = (const float4*)(W_ih + (size_t)g * KIN_);
  const float4* xe = (const float4*)(emb + b * EMB_);
  const float4* xw = (const float4*)(wgt + b * ENC_);
  float accx = b_ih[g];
  #pragma unroll 8
  for (int k = 0; k < EMB_ / 4; ++k) accx += dot4(wr[k], xe[k]);
  #pragma unroll 8
  for (int k = 0; k < ENC_ / 4; ++k) accx += dot4(wr[EMB_ / 4 + k], xw[k]);
  const float4* wh = (const float4*)(W_hh + (size_t)g * DEC_);
  const float4* xh = (const float4*)(h1 + b * DEC_);
  float acch = b_hh[g];
  #pragma unroll 5
  for (int k = 0; k < DEC_ / 4; ++k) acch += dot4(wh[k], xh[k]);
  gx[g * B_ + b] = accx;
  gh[g * B_ + b] = acch;
}

// GRU combine: h -> hn (f32), hwb bf16 [b,0:300], d_out tail, p_gen partial (h part).
__global__ __launch_bounds__(256) void k_gru_combine(const float* __restrict__ gx,
                                                     const float* __restrict__ gh,
                                                     const float* __restrict__ h1,
                                                     float* __restrict__ hn,
                                                     short* __restrict__ hwb,
                                                     float* __restrict__ outh,
                                                     const float* __restrict__ W_p,
                                                     float* __restrict__ pg_acc) {
  int j = blockIdx.x * 256 + threadIdx.x;
  int b = blockIdx.y;
  __shared__ float red[256];
  float pp = 0.f;
  if (j < DEC_) {
    float xr = gx[j * B_ + b], xz = gx[(j + DEC_) * B_ + b], xn = gx[(j + 2 * DEC_) * B_ + b];
    float hr = gh[j * B_ + b], hz = gh[(j + DEC_) * B_ + b], hnn = gh[(j + 2 * DEC_) * B_ + b];
    float r = 1.f / (1.f + __expf(-(xr + hr)));
    float z = 1.f / (1.f + __expf(-(xz + hz)));
    float n = tanhf(xn + r * hnn);
    float h = (1.f - z) * n + z * h1[b * DEC_ + j];
    hn[b * DEC_ + j] = h;
    hwb[(size_t)b * KHWP_ + j] = f2bf(h);
    outh[b * DEC_ + j] = h;
    pp = h * W_p[j];
  }
  red[threadIdx.x] = pp;
  __syncthreads();
  for (int st = 128; st > 0; st >>= 1) {
    if (threadIdx.x < st) red[threadIdx.x] += red[threadIdx.x + st];
    __syncthreads();
  }
  if (threadIdx.x == 0) atomicAdd(pg_acc + b, red[0]);
}

// logits = hwb . W_out^T + b_out via MFMA; per-tile (max, sumexp) partials.
// wml stats buffer ALIASES A_lds (dead after last MFMA ds_read) -> LDS stays 51200 B
// = 3 blocks/CU. Separate wml array (55296 B total) dropped us to 2 blocks/CU (r7).
__global__ __launch_bounds__(256, 3) void k_outproj(const short* __restrict__ A,
                                                    const float* __restrict__ Wo,
                                                    const float* __restrict__ bo,
                                                    float* __restrict__ out,
                                                    float* __restrict__ pml) {
  __shared__ __align__(16) short A_lds[B_ * ALDS_STRIDE_];  // 51200 B
  int tid = threadIdx.x;
  int wave = tid >> 6, lane = tid & 63;
  int r16 = lane & 15, kg = lane >> 4;
  int vcol = blockIdx.x * 64 + wave * 16 + r16;
  int vload = vcol < VOCAB_ ? vcol : VOCAB_ - 1;
  const float* brow = Wo + (size_t)vload * KHW_ + kg * 8;
  f32x4 acc[8];
  #pragma unroll
  for (int mi = 0; mi < 8; ++mi) acc[mi] = (f32x4){0.f, 0.f, 0.f, 0.f};

  short8 ar[12];
  float4 br[2][12];
  float  tl[8];

  #pragma unroll
  for (int i = 0; i < 12; ++i) {
    int g = tid + i * 256, row = g / 24, c8 = g % 24;
    ar[i] = *(const short8*)(A + (size_t)row * KHWP_ + c8 * 8);
  }
  #pragma unroll
  for (int s = 0; s < 6; ++s) {
    br[0][2 * s]     = *(const float4*)(brow + s * 32);
    br[0][2 * s + 1] = *(const float4*)(brow + s * 32 + 4);
  }

  #pragma unroll
  for (int c = 0; c < 7; ++c) {
    __syncthreads();
    #pragma unroll
    for (int i = 0; i < 12; ++i) {
      int g = tid + i * 256, row = g / 24, c8 = g % 24;
      *(short8*)(&A_lds[row * ALDS_STRIDE_ + c8 * 8]) = ar[i];
    }
    if (c < 6) {
      #pragma unroll
      for (int i = 0; i < 12; ++i) {
        int g = tid + i * 256, row = g / 24, c8 = g % 24;
        ar[i] = *(const short8*)(A + (size_t)row * KHWP_ + (c + 1) * CHK_ + c8 * 8);
      }
      if (c + 1 < 6) {
        #pragma unroll
        for (int s = 0; s < 6; ++s) {
          br[(c + 1) & 1][2 * s]     = *(const float4*)(brow + (c + 1) * CHK_ + s * 32);
          br[(c + 1) & 1][2 * s + 1] = *(const float4*)(brow + (c + 1) * CHK_ + s * 32 + 4);
        }
      } else {
        #pragma unroll
        for (int s = 0; s < 5; ++s) {
          br[0][2 * s]     = *(const float4*)(brow + 6 * CHK_ + s * 32);
          br[0][2 * s + 1] = *(const float4*)(brow + 6 * CHK_ + s * 32 + 4);
        }
        #pragma unroll
        for (int j = 0; j < 8; ++j)
          tl[j] = (kg * 8 + j < KHW_ - 1312) ? brow[1312 + j] : 0.f;
      }
    }
    __syncthreads();
    #pragma unroll
    for (int s = 0; s < 6; ++s) {
      short8 bf;
      if (c == 6 && s == 5) {
        #pragma unroll
        for (int j = 0; j < 8; ++j) bf[j] = f2bf(tl[j]);
      } else {
        float4 b0 = br[c & 1][2 * s], b1 = br[c & 1][2 * s + 1];
        bf[0] = f2bf(b0.x); bf[1] = f2bf(b0.y); bf[2] = f2bf(b0.z); bf[3] = f2bf(b0.w);
        bf[4] = f2bf(b1.x); bf[5] = f2bf(b1.y); bf[6] = f2bf(b1.z); bf[7] = f2bf(b1.w);
      }
      #pragma unroll
      for (int mi = 0; mi < 8; ++mi) {
        short8 af = *(const short8*)(&A_lds[(mi * 16 + r16) * ALDS_STRIDE_ + s * 32 + kg * 8]);
        acc[mi] = __builtin_amdgcn_mfma_f32_16x16x32_bf16(af, bf, acc[mi], 0, 0, 0);
      }
    }
  }

  __syncthreads();  // drain all A_lds reads; staging buffer now dead -> reuse for stats
  float* wml = (float*)A_lds;  // [4][B_][2] floats = 4096 B, aliased into 51200 B

  bool valid = vcol < VOCAB_;
  float biasv = bo[vload];
  #pragma unroll
  for (int mi = 0; mi < 8; ++mi) {
    #pragma unroll
    for (int j = 0; j < 4; ++j) {
      float lv = valid ? acc[mi][j] + biasv : -INFINITY;
      if (valid) out[(size_t)(mi * 16 + kg * 4 + j) * OUTW_ + vcol] = lv;
      float mr = lv;
      #pragma unroll
      for (int msk = 1; msk < 16; msk <<= 1) mr = fmaxf(mr, __shfl_xor(mr, msk));
      float se = valid ? __expf(lv - mr) : 0.f;
      #pragma unroll
      for (int msk = 1; msk < 16; msk <<= 1) se += __shfl_xor(se, msk);
      if (r16 == 0) {
        wml[(wave * B_ + mi * 16 + kg * 4 + j) * 2]     = mr;
        wml[(wave * B_ + mi * 16 + kg * 4 + j) * 2 + 1] = se;
      }
    }
  }
  __syncthreads();
  if (tid < B_) {
    float M = -INFINITY;
    #pragma unroll
    for (int w = 0; w < 4; ++w) M = fmaxf(M, wml[(w * B_ + tid) * 2]);
    float L = 0.f;
    #pragma unroll
    for (int w = 0; w < 4; ++w) {
      float lw = wml[(w * B_ + tid) * 2 + 1];
      if (lw > 0.f) L += lw * __expf(wml[(w * B_ + tid) * 2] - M);
    }
    pml[((size_t)blockIdx.x * B_ + tid) * 2]     = M;
    pml[((size_t)blockIdx.x * B_ + tid) * 2 + 1] = L;
  }
}

// Merge tile partials -> global (M,L); scale vocab region; zero OOV. 4 blocks per b.
__global__ __launch_bounds__(256) void k_vfinal(float* __restrict__ out,
                                                const float* __restrict__ pml,
                                                const float* __restrict__ pg,
                                                float* __restrict__ mlv) {
  int bq = blockIdx.x, b = blockIdx.y, t = threadIdx.x;
  __shared__ float rm[256], rl[256];
  float lm = -INFINITY, ll = 0.f;
  for (int tile = t; tile < NTILE_; tile += 256) {
    float m = pml[((size_t)tile * B_ + b) * 2];
    float l = pml[((size_t)tile * B_ + b) * 2 + 1];
    float M = fmaxf(lm, m);
    float nl = 0.f;
    if (ll > 0.f) nl += ll * __expf(lm - M);
    if (l > 0.f) nl += l * __expf(m - M);
    lm = M; ll = nl;
  }
  rm[t] = lm; rl[t] = ll;
  __syncthreads();
  for (int st = 128; st > 0; st >>= 1) {
    if (t < st) {
      float m1 = rm[t], l1 = rl[t], m2 = rm[t + st], l2 = rl[t + st];
      float M = fmaxf(m1, m2);
      float L = (l1 > 0.f ? l1 * __expf(m1 - M) : 0.f) + (l2 > 0.f ? l2 * __expf(m2 - M) : 0.f);
      rm[t] = M; rl[t] = L;
    }
    __syncthreads();
  }
  float M = rm[0], L = rl[0];
  float scale = pg[b] / L;
  float* row = out + (size_t)b * OUTW_;
  int lo = bq * 12513;
  int hi = min(lo + 12513, OUTW_);
  for (int v = lo + t; v < hi; v += 256)
    row[v] = (v < VOCAB_) ? scale * __expf(row[v] - M) : 0.f;
  if (bq == 0 && t == 0) { mlv[b * 2] = M; mlv[b * 2 + 1] = L; }
}

// Copy-mechanism scatter (after vfinal): p_out[b, src] += (1-pg)*a2
__global__ __launch_bounds__(256) void k_scatter2(float* __restrict__ out,
                                                  const int* __restrict__ src,
                                                  const float* __restrict__ scores,
                                                  const float* __restrict__ ml2,
                                                  const float* __restrict__ pg) {
  int b = blockIdx.x, t = threadIdx.x;
  float M2 = ml2[b * 2], L2 = ml2[b * 2 + 1];
  float q = (1.f - pg[b]) / L2;
  float* row = out + (size_t)b * OUTW_;
  for (int s = t; s < S_; s += 256) {
    float val = q * __expf(scores[b * S_ + s] - M2);
    atomicAdd(row + src[b * S_ + s], val);
  }
}

extern "C" void kernel_launch(void* const* d_in, const int* in_sizes, int n_in,
                              void* d_out, int out_size, void* d_ws, size_t ws_size,
                              hipStream_t stream) {
  const float* embedded = (const float*)d_in[0];
  const float* enc      = (const float*)d_in[1];
  const float* h1       = (const float*)d_in[2];
  const int*   src      = (const int*)d_in[5];
  const float* W1       = (const float*)d_in[6];
  const float* W2       = (const float*)d_in[7];
  const float* W_ih     = (const float*)d_in[8];
  const float* W_hh     = (const float*)d_in[9];
  const float* b_ih     = (const float*)d_in[10];
  const float* b_hh     = (const float*)d_in[11];
  const float* W_out    = (const float*)d_in[12];
  const float* b_out    = (const float*)d_in[13];
  const float* W_p      = (const float*)d_in[14];
  const float* b_p      = (const float*)d_in[15];
  float* out = (float*)d_out;
  float* ws  = (float*)d_ws;

  // Workspace (cumulative, no overlaps; ~21 MB total, ws is ~1 GB)
  size_t off = 0;
  float* v_ws    = ws + off; off += (size_t)B_ * ENC_;      // 131072
  float* w1_ws   = ws + off; off += (size_t)B_ * ENC_;      // 131072
  float* gx_ws   = ws + off; off += (size_t)G3_ * B_;       // 115200
  float* gh_ws   = ws + off; off += (size_t)G3_ * B_;       // 115200
  float* hn_ws   = ws + off; off += (size_t)B_ * DEC_;      // 38400
  float* sc_ws   = ws + off; off += (size_t)B_ * S_;        // 51200
  float* ml2_ws  = ws + off; off += 256;
  float* pg_ws   = ws + off; off += 128;
  float* pga_ws  = ws + off; off += 128;
  float* mlv_ws  = ws + off; off += 256;
  float* pml_ws  = ws + off; off += (size_t)NTILE_ * B_ * 2; // 200192
  short* hwb_ws  = (short*)(ws + off); off += (size_t)B_ * KHWP_ / 2;  // 86016
  float* part_ws = ws + off;                                 // B*NS*4*PSTRIDE

  int NS = 8;
  while (NS > 1 && (off + (size_t)B_ * NS * 4 * PSTRIDE_) * 4 > ws_size) NS >>= 1;

  // attention 1 -> w1 (flash, one enc sweep)
  k_compute_v<<<B_, 256, 0, stream>>>(W1, h1, v_ws);
  k_attn_pass<<<dim3(B_, NS), 256, 0, stream>>>(enc, v_ws, sc_ws, part_ws, NS);
  k_attn_merge1<<<B_, 256, 0, stream>>>(part_ws, NS * 4, w1_ws);
  // GRU -> h_new (hn f32; hwb bf16 h-part; d_out tail; pg h-partial)
  k_gates<<<(G3_ * B_) / 256, 256, 0, stream>>>(embedded, w1_ws, h1, W_ih, W_hh, b_ih, b_hh,
                                                gx_ws, gh_ws, pga_ws);
  k_gru_combine<<<dim3(2, B_), 256, 0, stream>>>(gx_ws, gh_ws, h1, hn_ws, hwb_ws,
                                                 out + (size_t)B_ * OUTW_, W_p, pga_ws);
  // attention 2 -> hwb w2-part, ml2, p_gen finished
  k_compute_v<<<B_, 256, 0, stream>>>(W2, hn_ws, v_ws);
  k_attn_pass<<<dim3(B_, NS), 256, 0, stream>>>(enc, v_ws, sc_ws, part_ws, NS);
  k_attn_merge2<<<B_, 256, 0, stream>>>(part_ws, NS * 4, hwb_ws, ml2_ws, W_p, b_p,
                                        pga_ws, pg_ws);
  // vocab projection (+ per-tile softmax partials), merge+scale, scatter
  k_outproj<<<NTILE_, 256, 0, stream>>>(hwb_ws, W_out, b_out, out, pml_ws);
  k_vfinal<<<dim3(4, B_), 256, 0, stream>>>(out, pml_ws, pg_ws, mlv_ws);
  k_scatter2<<<B_, 256, 0, stream>>>(out, src, sc_ws, ml2_ws, pg_ws);
}

// Round 9
// 488.172 us; speedup vs baseline: 1.0808x; 1.0808x over previous
//
#include <hip/hip_runtime.h>
#include <stdint.h>

constexpr int B_     = 128;
constexpr int S_     = 400;
constexpr int EMB_   = 128;
constexpr int ENC_   = 1024;
constexpr int DEC_   = 300;
constexpr int VOCAB_ = 50000;
constexpr int OOV_   = 50;
constexpr int OUTW_  = VOCAB_ + OOV_;   // 50050
constexpr int KHW_   = ENC_ + DEC_;     // 1324
constexpr int KHWP_  = 1344;            // 7*192, zero-padded K for MFMA
constexpr int G3_    = 3 * DEC_;        // 900
constexpr int KIN_   = EMB_ + ENC_;     // 1152
constexpr int CHK_   = 192;             // K-chunk staged in LDS (outproj)
constexpr int ALDS_STRIDE_ = 200;       // bf16 elems; 400B row stride
constexpr int PSTRIDE_ = 1028;          // flash partial: 1024 wa + m + l (+pad)
constexpr int NTILE_ = 782;             // outproj col tiles (64 each)

typedef __attribute__((ext_vector_type(4))) float f32x4;
typedef __attribute__((ext_vector_type(8))) short short8;

__device__ __forceinline__ float dot4(float4 a, float4 b) {
  return a.x * b.x + a.y * b.y + a.z * b.z + a.w * b.w;
}

__device__ __forceinline__ short f2bf(float f) {  // RNE f32 -> bf16
  uint32_t u = __builtin_bit_cast(uint32_t, f);
  u += 0x7fffu + ((u >> 16) & 1u);
  return (short)(u >> 16);
}

// v[b,e] = sum_d W[e,d] * h[b,d]
__global__ __launch_bounds__(256) void k_compute_v(const float* __restrict__ W,
                                                   const float* __restrict__ h,
                                                   float* __restrict__ v) {
  int b = blockIdx.x;
  __shared__ __align__(16) float hs[DEC_];
  for (int d = threadIdx.x; d < DEC_; d += 256) hs[d] = h[b * DEC_ + d];
  __syncthreads();
  for (int e = threadIdx.x; e < ENC_; e += 256) {
    const float4* w4 = (const float4*)(W + (size_t)e * DEC_);
    const float4* h4 = (const float4*)hs;
    float acc = 0.f;
    #pragma unroll 5
    for (int d = 0; d < DEC_ / 4; ++d) acc += dot4(w4[d], h4[d]);
    v[b * ENC_ + e] = acc;
  }
}

// Flash pass, 2-row ILP: scores + online softmax-weighted enc sum; per-wave partials.
__global__ __launch_bounds__(256) void k_attn_pass(const float* __restrict__ enc,
                                                   const float* __restrict__ v,
                                                   float* __restrict__ scores,
                                                   float* __restrict__ part, int nsplit) {
  int b = blockIdx.x, split = blockIdx.y;
  int wave = threadIdx.x >> 6, lane = threadIdx.x & 63;
  float4 vr[4];
  #pragma unroll
  for (int c = 0; c < 4; ++c) vr[c] = *(const float4*)(v + b * ENC_ + c * 256 + lane * 4);
  float m = -INFINITY, l = 0.f;
  float4 wa[4];
  #pragma unroll
  for (int c = 0; c < 4; ++c) wa[c] = make_float4(0.f, 0.f, 0.f, 0.f);
  int rows = S_ / nsplit, s0 = split * rows, s_end = s0 + rows;
  int s = s0 + wave;
  for (; s + 4 < s_end; s += 8) {
    const float* era = enc + ((size_t)b * S_ + s) * ENC_;
    const float* erb = enc + ((size_t)b * S_ + s + 4) * ENC_;
    float4 e4a[4], e4b[4];
    #pragma unroll
    for (int c = 0; c < 4; ++c) {
      e4a[c] = *(const float4*)(era + c * 256 + lane * 4);
      e4b[c] = *(const float4*)(erb + c * 256 + lane * 4);
    }
    float pa = 0.f, pb = 0.f;
    #pragma unroll
    for (int c = 0; c < 4; ++c) { pa += dot4(e4a[c], vr[c]); pb += dot4(e4b[c], vr[c]); }
    #pragma unroll
    for (int off = 32; off; off >>= 1) {
      pa += __shfl_xor(pa, off);
      pb += __shfl_xor(pb, off);
    }
    if (lane == 0) { scores[b * S_ + s] = pa; scores[b * S_ + s + 4] = pb; }
    float nm = fmaxf(m, fmaxf(pa, pb));
    float sc = __expf(m - nm);
    float ea = __expf(pa - nm);
    float eb = __expf(pb - nm);
    l = l * sc + ea + eb;
    #pragma unroll
    for (int c = 0; c < 4; ++c) {
      wa[c].x = wa[c].x * sc + ea * e4a[c].x + eb * e4b[c].x;
      wa[c].y = wa[c].y * sc + ea * e4a[c].y + eb * e4b[c].y;
      wa[c].z = wa[c].z * sc + ea * e4a[c].z + eb * e4b[c].z;
      wa[c].w = wa[c].w * sc + ea * e4a[c].w + eb * e4b[c].w;
    }
    m = nm;
  }
  if (s < s_end) {  // tail single row
    const float* er = enc + ((size_t)b * S_ + s) * ENC_;
    float4 e4[4];
    #pragma unroll
    for (int c = 0; c < 4; ++c) e4[c] = *(const float4*)(er + c * 256 + lane * 4);
    float p = 0.f;
    #pragma unroll
    for (int c = 0; c < 4; ++c) p += dot4(e4[c], vr[c]);
    #pragma unroll
    for (int off = 32; off; off >>= 1) p += __shfl_xor(p, off);
    if (lane == 0) scores[b * S_ + s] = p;
    float nm = fmaxf(m, p);
    float sc = __expf(m - nm), pe = __expf(p - nm);
    l = l * sc + pe;
    #pragma unroll
    for (int c = 0; c < 4; ++c) {
      wa[c].x = wa[c].x * sc + pe * e4[c].x;
      wa[c].y = wa[c].y * sc + pe * e4[c].y;
      wa[c].z = wa[c].z * sc + pe * e4[c].z;
      wa[c].w = wa[c].w * sc + pe * e4[c].w;
    }
    m = nm;
  }
  float* pp = part + ((size_t)b * (nsplit * 4) + split * 4 + wave) * PSTRIDE_;
  #pragma unroll
  for (int c = 0; c < 4; ++c) *(float4*)(pp + c * 256 + lane * 4) = wa[c];
  if (lane == 0) { pp[1024] = m; pp[1025] = l; }
}

// Merge partials -> w1[b,:] (f32) for GRU input
__global__ __launch_bounds__(256) void k_attn_merge1(const float* __restrict__ part, int P,
                                                     float* __restrict__ wout) {
  int b = blockIdx.x, tid = threadIdx.x;
  const float* pb = part + (size_t)b * P * PSTRIDE_;
  __shared__ float scl[32];
  __shared__ float Ls;
  if (tid == 0) {
    float M = -INFINITY;
    for (int p = 0; p < P; ++p) M = fmaxf(M, pb[p * PSTRIDE_ + 1024]);
    float L = 0.f;
    for (int p = 0; p < P; ++p) {
      float lp = pb[p * PSTRIDE_ + 1025];
      float e = (lp > 0.f) ? __expf(pb[p * PSTRIDE_ + 1024] - M) : 0.f;
      scl[p] = e;
      L += lp * e;
    }
    Ls = L;
  }
  __syncthreads();
  float invL = 1.f / Ls;
  for (int e = tid; e < ENC_; e += 256) {
    float acc = 0.f;
    for (int p = 0; p < P; ++p) acc += scl[p] * pb[p * PSTRIDE_ + e];
    wout[(size_t)b * ENC_ + e] = acc * invL;
  }
}

// Merge partials (attn2) -> hwb bf16 [b,300:1324], ml2, and finish p_gen.
__global__ __launch_bounds__(256) void k_attn_merge2(const float* __restrict__ part, int P,
                                                     short* __restrict__ hwb,
                                                     float* __restrict__ ml,
                                                     const float* __restrict__ W_p,
                                                     const float* __restrict__ b_p,
                                                     const float* __restrict__ pg_acc,
                                                     float* __restrict__ pg) {
  int b = blockIdx.x, tid = threadIdx.x;
  const float* pb = part + (size_t)b * P * PSTRIDE_;
  __shared__ float scl[32];
  __shared__ float Ls;
  __shared__ float red[256];
  if (tid == 0) {
    float M = -INFINITY;
    for (int p = 0; p < P; ++p) M = fmaxf(M, pb[p * PSTRIDE_ + 1024]);
    float L = 0.f;
    for (int p = 0; p < P; ++p) {
      float lp = pb[p * PSTRIDE_ + 1025];
      float e = (lp > 0.f) ? __expf(pb[p * PSTRIDE_ + 1024] - M) : 0.f;
      scl[p] = e;
      L += lp * e;
    }
    Ls = L;
    ml[b * 2] = M; ml[b * 2 + 1] = L;
  }
  __syncthreads();
  float invL = 1.f / Ls;
  float pacc = 0.f;
  for (int e = tid; e < ENC_; e += 256) {
    float acc = 0.f;
    for (int p = 0; p < P; ++p) acc += scl[p] * pb[p * PSTRIDE_ + e];
    float w = acc * invL;
    hwb[(size_t)b * KHWP_ + DEC_ + e] = f2bf(w);
    pacc += w * W_p[DEC_ + e];
  }
  if (tid < KHWP_ - KHW_) hwb[(size_t)b * KHWP_ + KHW_ + tid] = 0;  // zero pad
  red[tid] = pacc;
  __syncthreads();
  for (int st = 128; st > 0; st >>= 1) {
    if (tid < st) red[tid] += red[tid + st];
    __syncthreads();
  }
  if (tid == 0) pg[b] = 1.f / (1.f + __expf(-(red[0] + pg_acc[b] + b_p[0])));
}

// GRU gate pre-activations: gx[g,b], gh[g,b]; also zeroes pg_acc.
__global__ __launch_bounds__(256) void k_gates(const float* __restrict__ emb,
                                               const float* __restrict__ wgt,
                                               const float* __restrict__ h1,
                                               const float* __restrict__ W_ih,
                                               const float* __restrict__ W_hh,
                                               const float* __restrict__ b_ih,
                                               const float* __restrict__ b_hh,
                                               float* __restrict__ gx, float* __restrict__ gh,
                                               float* __restrict__ pg_acc) {
  int idx = blockIdx.x * 256 + threadIdx.x;
  if (idx < B_) pg_acc[idx] = 0.f;
  int b = idx & (B_ - 1);
  int g = idx >> 7;
  if (g >= G3_) return;
  const float4* wr = (const float4*)(W_ih + (size_t)g * KIN_);
  const float4* xe = (const float4*)(emb + b * EMB_);
  const float4* xw = (const float4*)(wgt + b * ENC_);
  float accx = b_ih[g];
  #pragma unroll 8
  for (int k = 0; k < EMB_ / 4; ++k) accx += dot4(wr[k], xe[k]);
  #pragma unroll 8
  for (int k = 0; k < ENC_ / 4; ++k) accx += dot4(wr[EMB_ / 4 + k], xw[k]);
  const float4* wh = (const float4*)(W_hh + (size_t)g * DEC_);
  const float4* xh = (const float4*)(h1 + b * DEC_);
  float acch = b_hh[g];
  #pragma unroll 5
  for (int k = 0; k < DEC_ / 4; ++k) acch += dot4(wh[k], xh[k]);
  gx[g * B_ + b] = accx;
  gh[g * B_ + b] = acch;
}

// GRU combine: h -> hn (f32), hwb bf16 [b,0:300], d_out tail, p_gen partial (h part).
__global__ __launch_bounds__(256) void k_gru_combine(const float* __restrict__ gx,
                                                     const float* __restrict__ gh,
                                                     const float* __restrict__ h1,
                                                     float* __restrict__ hn,
                                                     short* __restrict__ hwb,
                                                     float* __restrict__ outh,
                                                     const float* __restrict__ W_p,
                                                     float* __restrict__ pg_acc) {
  int j = blockIdx.x * 256 + threadIdx.x;
  int b = blockIdx.y;
  __shared__ float red[256];
  float pp = 0.f;
  if (j < DEC_) {
    float xr = gx[j * B_ + b], xz = gx[(j + DEC_) * B_ + b], xn = gx[(j + 2 * DEC_) * B_ + b];
    float hr = gh[j * B_ + b], hz = gh[(j + DEC_) * B_ + b], hnn = gh[(j + 2 * DEC_) * B_ + b];
    float r = 1.f / (1.f + __expf(-(xr + hr)));
    float z = 1.f / (1.f + __expf(-(xz + hz)));
    float n = tanhf(xn + r * hnn);
    float h = (1.f - z) * n + z * h1[b * DEC_ + j];
    hn[b * DEC_ + j] = h;
    hwb[(size_t)b * KHWP_ + j] = f2bf(h);
    outh[b * DEC_ + j] = h;
    pp = h * W_p[j];
  }
  red[threadIdx.x] = pp;
  __syncthreads();
  for (int st = 128; st > 0; st >>= 1) {
    if (threadIdx.x < st) red[threadIdx.x] += red[threadIdx.x + st];
    __syncthreads();
  }
  if (threadIdx.x == 0) atomicAdd(pg_acc + b, red[0]);
}

// logits = hwb . W_out^T + b_out via MFMA; per-tile (max, sumexp) partials.
// wml stats ALIAS A_lds (dead after last MFMA ds_read) -> LDS 51200 B = 3 blocks/CU.
// NOTE: plain __launch_bounds__(256). Adding ",3" in r8 forced VGPR 132->84 and
// spilled the br[] double-buffer to scratch: FETCH +83MB, WRITE +135MB, 195 us.
__global__ __launch_bounds__(256) void k_outproj(const short* __restrict__ A,
                                                 const float* __restrict__ Wo,
                                                 const float* __restrict__ bo,
                                                 float* __restrict__ out,
                                                 float* __restrict__ pml) {
  __shared__ __align__(16) short A_lds[B_ * ALDS_STRIDE_];  // 51200 B
  int tid = threadIdx.x;
  int wave = tid >> 6, lane = tid & 63;
  int r16 = lane & 15, kg = lane >> 4;
  int vcol = blockIdx.x * 64 + wave * 16 + r16;
  int vload = vcol < VOCAB_ ? vcol : VOCAB_ - 1;
  const float* brow = Wo + (size_t)vload * KHW_ + kg * 8;
  f32x4 acc[8];
  #pragma unroll
  for (int mi = 0; mi < 8; ++mi) acc[mi] = (f32x4){0.f, 0.f, 0.f, 0.f};

  short8 ar[12];
  float4 br[2][12];
  float  tl[8];

  #pragma unroll
  for (int i = 0; i < 12; ++i) {
    int g = tid + i * 256, row = g / 24, c8 = g % 24;
    ar[i] = *(const short8*)(A + (size_t)row * KHWP_ + c8 * 8);
  }
  #pragma unroll
  for (int s = 0; s < 6; ++s) {
    br[0][2 * s]     = *(const float4*)(brow + s * 32);
    br[0][2 * s + 1] = *(const float4*)(brow + s * 32 + 4);
  }

  #pragma unroll
  for (int c = 0; c < 7; ++c) {
    __syncthreads();
    #pragma unroll
    for (int i = 0; i < 12; ++i) {
      int g = tid + i * 256, row = g / 24, c8 = g % 24;
      *(short8*)(&A_lds[row * ALDS_STRIDE_ + c8 * 8]) = ar[i];
    }
    if (c < 6) {
      #pragma unroll
      for (int i = 0; i < 12; ++i) {
        int g = tid + i * 256, row = g / 24, c8 = g % 24;
        ar[i] = *(const short8*)(A + (size_t)row * KHWP_ + (c + 1) * CHK_ + c8 * 8);
      }
      if (c + 1 < 6) {
        #pragma unroll
        for (int s = 0; s < 6; ++s) {
          br[(c + 1) & 1][2 * s]     = *(const float4*)(brow + (c + 1) * CHK_ + s * 32);
          br[(c + 1) & 1][2 * s + 1] = *(const float4*)(brow + (c + 1) * CHK_ + s * 32 + 4);
        }
      } else {
        #pragma unroll
        for (int s = 0; s < 5; ++s) {
          br[0][2 * s]     = *(const float4*)(brow + 6 * CHK_ + s * 32);
          br[0][2 * s + 1] = *(const float4*)(brow + 6 * CHK_ + s * 32 + 4);
        }
        #pragma unroll
        for (int j = 0; j < 8; ++j)
          tl[j] = (kg * 8 + j < KHW_ - 1312) ? brow[1312 + j] : 0.f;
      }
    }
    __syncthreads();
    #pragma unroll
    for (int s = 0; s < 6; ++s) {
      short8 bf;
      if (c == 6 && s == 5) {
        #pragma unroll
        for (int j = 0; j < 8; ++j) bf[j] = f2bf(tl[j]);
      } else {
        float4 b0 = br[c & 1][2 * s], b1 = br[c & 1][2 * s + 1];
        bf[0] = f2bf(b0.x); bf[1] = f2bf(b0.y); bf[2] = f2bf(b0.z); bf[3] = f2bf(b0.w);
        bf[4] = f2bf(b1.x); bf[5] = f2bf(b1.y); bf[6] = f2bf(b1.z); bf[7] = f2bf(b1.w);
      }
      #pragma unroll
      for (int mi = 0; mi < 8; ++mi) {
        short8 af = *(const short8*)(&A_lds[(mi * 16 + r16) * ALDS_STRIDE_ + s * 32 + kg * 8]);
        acc[mi] = __builtin_amdgcn_mfma_f32_16x16x32_bf16(af, bf, acc[mi], 0, 0, 0);
      }
    }
  }

  __syncthreads();  // drain all A_lds reads; staging buffer now dead -> reuse for stats
  float* wml = (float*)A_lds;  // [4][B_][2] floats = 4096 B, aliased into 51200 B

  bool valid = vcol < VOCAB_;
  float biasv = bo[vload];
  #pragma unroll
  for (int mi = 0; mi < 8; ++mi) {
    #pragma unroll
    for (int j = 0; j < 4; ++j) {
      float lv = valid ? acc[mi][j] + biasv : -INFINITY;
      if (valid) out[(size_t)(mi * 16 + kg * 4 + j) * OUTW_ + vcol] = lv;
      float mr = lv;
      #pragma unroll
      for (int msk = 1; msk < 16; msk <<= 1) mr = fmaxf(mr, __shfl_xor(mr, msk));
      float se = valid ? __expf(lv - mr) : 0.f;
      #pragma unroll
      for (int msk = 1; msk < 16; msk <<= 1) se += __shfl_xor(se, msk);
      if (r16 == 0) {
        wml[(wave * B_ + mi * 16 + kg * 4 + j) * 2]     = mr;
        wml[(wave * B_ + mi * 16 + kg * 4 + j) * 2 + 1] = se;
      }
    }
  }
  __syncthreads();
  if (tid < B_) {
    float M = -INFINITY;
    #pragma unroll
    for (int w = 0; w < 4; ++w) M = fmaxf(M, wml[(w * B_ + tid) * 2]);
    float L = 0.f;
    #pragma unroll
    for (int w = 0; w < 4; ++w) {
      float lw = wml[(w * B_ + tid) * 2 + 1];
      if (lw > 0.f) L += lw * __expf(wml[(w * B_ + tid) * 2] - M);
    }
    pml[((size_t)blockIdx.x * B_ + tid) * 2]     = M;
    pml[((size_t)blockIdx.x * B_ + tid) * 2 + 1] = L;
  }
}

// Merge tile partials -> global (M,L); scale vocab region; zero OOV. 4 blocks per b.
__global__ __launch_bounds__(256) void k_vfinal(float* __restrict__ out,
                                                const float* __restrict__ pml,
                                                const float* __restrict__ pg,
                                                float* __restrict__ mlv) {
  int bq = blockIdx.x, b = blockIdx.y, t = threadIdx.x;
  __shared__ float rm[256], rl[256];
  float lm = -INFINITY, ll = 0.f;
  for (int tile = t; tile < NTILE_; tile += 256) {
    float m = pml[((size_t)tile * B_ + b) * 2];
    float l = pml[((size_t)tile * B_ + b) * 2 + 1];
    float M = fmaxf(lm, m);
    float nl = 0.f;
    if (ll > 0.f) nl += ll * __expf(lm - M);
    if (l > 0.f) nl += l * __expf(m - M);
    lm = M; ll = nl;
  }
  rm[t] = lm; rl[t] = ll;
  __syncthreads();
  for (int st = 128; st > 0; st >>= 1) {
    if (t < st) {
      float m1 = rm[t], l1 = rl[t], m2 = rm[t + st], l2 = rl[t + st];
      float M = fmaxf(m1, m2);
      float L = (l1 > 0.f ? l1 * __expf(m1 - M) : 0.f) + (l2 > 0.f ? l2 * __expf(m2 - M) : 0.f);
      rm[t] = M; rl[t] = L;
    }
    __syncthreads();
  }
  float M = rm[0], L = rl[0];
  float scale = pg[b] / L;
  float* row = out + (size_t)b * OUTW_;
  int lo = bq * 12513;
  int hi = min(lo + 12513, OUTW_);
  for (int v = lo + t; v < hi; v += 256)
    row[v] = (v < VOCAB_) ? scale * __expf(row[v] - M) : 0.f;
  if (bq == 0 && t == 0) { mlv[b * 2] = M; mlv[b * 2 + 1] = L; }
}

// Copy-mechanism scatter (after vfinal): p_out[b, src] += (1-pg)*a2
__global__ __launch_bounds__(256) void k_scatter2(float* __restrict__ out,
                                                  const int* __restrict__ src,
                                                  const float* __restrict__ scores,
                                                  const float* __restrict__ ml2,
                                                  const float* __restrict__ pg) {
  int b = blockIdx.x, t = threadIdx.x;
  float M2 = ml2[b * 2], L2 = ml2[b * 2 + 1];
  float q = (1.f - pg[b]) / L2;
  float* row = out + (size_t)b * OUTW_;
  for (int s = t; s < S_; s += 256) {
    float val = q * __expf(scores[b * S_ + s] - M2);
    atomicAdd(row + src[b * S_ + s], val);
  }
}

extern "C" void kernel_launch(void* const* d_in, const int* in_sizes, int n_in,
                              void* d_out, int out_size, void* d_ws, size_t ws_size,
                              hipStream_t stream) {
  const float* embedded = (const float*)d_in[0];
  const float* enc      = (const float*)d_in[1];
  const float* h1       = (const float*)d_in[2];
  const int*   src      = (const int*)d_in[5];
  const float* W1       = (const float*)d_in[6];
  const float* W2       = (const float*)d_in[7];
  const float* W_ih     = (const float*)d_in[8];
  const float* W_hh     = (const float*)d_in[9];
  const float* b_ih     = (const float*)d_in[10];
  const float* b_hh     = (const float*)d_in[11];
  const float* W_out    = (const float*)d_in[12];
  const float* b_out    = (const float*)d_in[13];
  const float* W_p      = (const float*)d_in[14];
  const float* b_p      = (const float*)d_in[15];
  float* out = (float*)d_out;
  float* ws  = (float*)d_ws;

  // Workspace (cumulative, no overlaps; ~21 MB total, ws is ~1 GB)
  size_t off = 0;
  float* v_ws    = ws + off; off += (size_t)B_ * ENC_;      // 131072
  float* w1_ws   = ws + off; off += (size_t)B_ * ENC_;      // 131072
  float* gx_ws   = ws + off; off += (size_t)G3_ * B_;       // 115200
  float* gh_ws   = ws + off; off += (size_t)G3_ * B_;       // 115200
  float* hn_ws   = ws + off; off += (size_t)B_ * DEC_;      // 38400
  float* sc_ws   = ws + off; off += (size_t)B_ * S_;        // 51200
  float* ml2_ws  = ws + off; off += 256;
  float* pg_ws   = ws + off; off += 128;
  float* pga_ws  = ws + off; off += 128;
  float* mlv_ws  = ws + off; off += 256;
  float* pml_ws  = ws + off; off += (size_t)NTILE_ * B_ * 2; // 200192
  short* hwb_ws  = (short*)(ws + off); off += (size_t)B_ * KHWP_ / 2;  // 86016
  float* part_ws = ws + off;                                 // B*NS*4*PSTRIDE

  int NS = 8;
  while (NS > 1 && (off + (size_t)B_ * NS * 4 * PSTRIDE_) * 4 > ws_size) NS >>= 1;

  // attention 1 -> w1 (flash, one enc sweep)
  k_compute_v<<<B_, 256, 0, stream>>>(W1, h1, v_ws);
  k_attn_pass<<<dim3(B_, NS), 256, 0, stream>>>(enc, v_ws, sc_ws, part_ws, NS);
  k_attn_merge1<<<B_, 256, 0, stream>>>(part_ws, NS * 4, w1_ws);
  // GRU -> h_new (hn f32; hwb bf16 h-part; d_out tail; pg h-partial)
  k_gates<<<(G3_ * B_) / 256, 256, 0, stream>>>(embedded, w1_ws, h1, W_ih, W_hh, b_ih, b_hh,
                                                gx_ws, gh_ws, pga_ws);
  k_gru_combine<<<dim3(2, B_), 256, 0, stream>>>(gx_ws, gh_ws, h1, hn_ws, hwb_ws,
                                                 out + (size_t)B_ * OUTW_, W_p, pga_ws);
  // attention 2 -> hwb w2-part, ml2, p_gen finished
  k_compute_v<<<B_, 256, 0, stream>>>(W2, hn_ws, v_ws);
  k_attn_pass<<<dim3(B_, NS), 256, 0, stream>>>(enc, v_ws, sc_ws, part_ws, NS);
  k_attn_merge2<<<B_, 256, 0, stream>>>(part_ws, NS * 4, hwb_ws, ml2_ws, W_p, b_p,
                                        pga_ws, pg_ws);
  // vocab projection (+ per-tile softmax partials), merge+scale, scatter
  k_outproj<<<NTILE_, 256, 0, stream>>>(hwb_ws, W_out, b_out, out, pml_ws);
  k_vfinal<<<dim3(4, B_), 256, 0, stream>>>(out, pml_ws, pg_ws, mlv_ws);
  k_scatter2<<<B_, 256, 0, stream>>>(out, src, sc_ws, ml2_ws, pg_ws);
}

// Round 10
// 474.966 us; speedup vs baseline: 1.1109x; 1.0278x over previous
//
#include <hip/hip_runtime.h>
#include <stdint.h>

constexpr int B_     = 128;
constexpr int S_     = 400;
constexpr int EMB_   = 128;
constexpr int ENC_   = 1024;
constexpr int DEC_   = 300;
constexpr int VOCAB_ = 50000;
constexpr int OOV_   = 50;
constexpr int OUTW_  = VOCAB_ + OOV_;   // 50050
constexpr int KHW_   = ENC_ + DEC_;     // 1324
constexpr int KHWP_  = 1344;            // 7*192, zero-padded K for MFMA
constexpr int G3_    = 3 * DEC_;        // 900
constexpr int KIN_   = EMB_ + ENC_;     // 1152
constexpr int CHK_   = 192;             // K-chunk staged in LDS (outproj)
constexpr int ALDS_STRIDE_ = 200;       // bf16 elems; 400B row stride
constexpr int PSTRIDE_ = 1028;          // flash partial: 1024 wa + m + l (+pad)
constexpr int NTILE_ = 782;             // outproj col tiles (64 each)

typedef __attribute__((ext_vector_type(4))) float f32x4;
typedef __attribute__((ext_vector_type(8))) short short8;

__device__ __forceinline__ float dot4(float4 a, float4 b) {
  return a.x * b.x + a.y * b.y + a.z * b.z + a.w * b.w;
}

__device__ __forceinline__ short f2bf(float f) {  // RNE f32 -> bf16
  uint32_t u = __builtin_bit_cast(uint32_t, f);
  u += 0x7fffu + ((u >> 16) & 1u);
  return (short)(u >> 16);
}

// v[b,e] = sum_d W[e,d] * h[b,d]
__global__ __launch_bounds__(256) void k_compute_v(const float* __restrict__ W,
                                                   const float* __restrict__ h,
                                                   float* __restrict__ v) {
  int b = blockIdx.x;
  __shared__ __align__(16) float hs[DEC_];
  for (int d = threadIdx.x; d < DEC_; d += 256) hs[d] = h[b * DEC_ + d];
  __syncthreads();
  for (int e = threadIdx.x; e < ENC_; e += 256) {
    const float4* w4 = (const float4*)(W + (size_t)e * DEC_);
    const float4* h4 = (const float4*)hs;
    float acc = 0.f;
    #pragma unroll 5
    for (int d = 0; d < DEC_ / 4; ++d) acc += dot4(w4[d], h4[d]);
    v[b * ENC_ + e] = acc;
  }
}

// Flash pass, 2-row ILP: scores + online softmax-weighted enc sum; per-wave partials.
__global__ __launch_bounds__(256) void k_attn_pass(const float* __restrict__ enc,
                                                   const float* __restrict__ v,
                                                   float* __restrict__ scores,
                                                   float* __restrict__ part, int nsplit) {
  int b = blockIdx.x, split = blockIdx.y;
  int wave = threadIdx.x >> 6, lane = threadIdx.x & 63;
  float4 vr[4];
  #pragma unroll
  for (int c = 0; c < 4; ++c) vr[c] = *(const float4*)(v + b * ENC_ + c * 256 + lane * 4);
  float m = -INFINITY, l = 0.f;
  float4 wa[4];
  #pragma unroll
  for (int c = 0; c < 4; ++c) wa[c] = make_float4(0.f, 0.f, 0.f, 0.f);
  int rows = S_ / nsplit, s0 = split * rows, s_end = s0 + rows;
  int s = s0 + wave;
  for (; s + 4 < s_end; s += 8) {
    const float* era = enc + ((size_t)b * S_ + s) * ENC_;
    const float* erb = enc + ((size_t)b * S_ + s + 4) * ENC_;
    float4 e4a[4], e4b[4];
    #pragma unroll
    for (int c = 0; c < 4; ++c) {
      e4a[c] = *(const float4*)(era + c * 256 + lane * 4);
      e4b[c] = *(const float4*)(erb + c * 256 + lane * 4);
    }
    float pa = 0.f, pb = 0.f;
    #pragma unroll
    for (int c = 0; c < 4; ++c) { pa += dot4(e4a[c], vr[c]); pb += dot4(e4b[c], vr[c]); }
    #pragma unroll
    for (int off = 32; off; off >>= 1) {
      pa += __shfl_xor(pa, off);
      pb += __shfl_xor(pb, off);
    }
    if (lane == 0) { scores[b * S_ + s] = pa; scores[b * S_ + s + 4] = pb; }
    float nm = fmaxf(m, fmaxf(pa, pb));
    float sc = __expf(m - nm);
    float ea = __expf(pa - nm);
    float eb = __expf(pb - nm);
    l = l * sc + ea + eb;
    #pragma unroll
    for (int c = 0; c < 4; ++c) {
      wa[c].x = wa[c].x * sc + ea * e4a[c].x + eb * e4b[c].x;
      wa[c].y = wa[c].y * sc + ea * e4a[c].y + eb * e4b[c].y;
      wa[c].z = wa[c].z * sc + ea * e4a[c].z + eb * e4b[c].z;
      wa[c].w = wa[c].w * sc + ea * e4a[c].w + eb * e4b[c].w;
    }
    m = nm;
  }
  if (s < s_end) {  // tail single row
    const float* er = enc + ((size_t)b * S_ + s) * ENC_;
    float4 e4[4];
    #pragma unroll
    for (int c = 0; c < 4; ++c) e4[c] = *(const float4*)(er + c * 256 + lane * 4);
    float p = 0.f;
    #pragma unroll
    for (int c = 0; c < 4; ++c) p += dot4(e4[c], vr[c]);
    #pragma unroll
    for (int off = 32; off; off >>= 1) p += __shfl_xor(p, off);
    if (lane == 0) scores[b * S_ + s] = p;
    float nm = fmaxf(m, p);
    float sc = __expf(m - nm), pe = __expf(p - nm);
    l = l * sc + pe;
    #pragma unroll
    for (int c = 0; c < 4; ++c) {
      wa[c].x = wa[c].x * sc + pe * e4[c].x;
      wa[c].y = wa[c].y * sc + pe * e4[c].y;
      wa[c].z = wa[c].z * sc + pe * e4[c].z;
      wa[c].w = wa[c].w * sc + pe * e4[c].w;
    }
    m = nm;
  }
  float* pp = part + ((size_t)b * (nsplit * 4) + split * 4 + wave) * PSTRIDE_;
  #pragma unroll
  for (int c = 0; c < 4; ++c) *(float4*)(pp + c * 256 + lane * 4) = wa[c];
  if (lane == 0) { pp[1024] = m; pp[1025] = l; }
}

// Merge partials -> w1[b,:] (f32) for GRU input
__global__ __launch_bounds__(256) void k_attn_merge1(const float* __restrict__ part, int P,
                                                     float* __restrict__ wout) {
  int b = blockIdx.x, tid = threadIdx.x;
  const float* pb = part + (size_t)b * P * PSTRIDE_;
  __shared__ float scl[32];
  __shared__ float Ls;
  if (tid == 0) {
    float M = -INFINITY;
    for (int p = 0; p < P; ++p) M = fmaxf(M, pb[p * PSTRIDE_ + 1024]);
    float L = 0.f;
    for (int p = 0; p < P; ++p) {
      float lp = pb[p * PSTRIDE_ + 1025];
      float e = (lp > 0.f) ? __expf(pb[p * PSTRIDE_ + 1024] - M) : 0.f;
      scl[p] = e;
      L += lp * e;
    }
    Ls = L;
  }
  __syncthreads();
  float invL = 1.f / Ls;
  for (int e = tid; e < ENC_; e += 256) {
    float acc = 0.f;
    for (int p = 0; p < P; ++p) acc += scl[p] * pb[p * PSTRIDE_ + e];
    wout[(size_t)b * ENC_ + e] = acc * invL;
  }
}

// Merge partials (attn2) -> hwb bf16 [b,300:1324], ml2, and finish p_gen.
__global__ __launch_bounds__(256) void k_attn_merge2(const float* __restrict__ part, int P,
                                                     short* __restrict__ hwb,
                                                     float* __restrict__ ml,
                                                     const float* __restrict__ W_p,
                                                     const float* __restrict__ b_p,
                                                     const float* __restrict__ pg_acc,
                                                     float* __restrict__ pg) {
  int b = blockIdx.x, tid = threadIdx.x;
  const float* pb = part + (size_t)b * P * PSTRIDE_;
  __shared__ float scl[32];
  __shared__ float Ls;
  __shared__ float red[256];
  if (tid == 0) {
    float M = -INFINITY;
    for (int p = 0; p < P; ++p) M = fmaxf(M, pb[p * PSTRIDE_ + 1024]);
    float L = 0.f;
    for (int p = 0; p < P; ++p) {
      float lp = pb[p * PSTRIDE_ + 1025];
      float e = (lp > 0.f) ? __expf(pb[p * PSTRIDE_ + 1024] - M) : 0.f;
      scl[p] = e;
      L += lp * e;
    }
    Ls = L;
    ml[b * 2] = M; ml[b * 2 + 1] = L;
  }
  __syncthreads();
  float invL = 1.f / Ls;
  float pacc = 0.f;
  for (int e = tid; e < ENC_; e += 256) {
    float acc = 0.f;
    for (int p = 0; p < P; ++p) acc += scl[p] * pb[p * PSTRIDE_ + e];
    float w = acc * invL;
    hwb[(size_t)b * KHWP_ + DEC_ + e] = f2bf(w);
    pacc += w * W_p[DEC_ + e];
  }
  if (tid < KHWP_ - KHW_) hwb[(size_t)b * KHWP_ + KHW_ + tid] = 0;  // zero pad
  red[tid] = pacc;
  __syncthreads();
  for (int st = 128; st > 0; st >>= 1) {
    if (tid < st) red[tid] += red[tid + st];
    __syncthreads();
  }
  if (tid == 0) pg[b] = 1.f / (1.f + __expf(-(red[0] + pg_acc[b] + b_p[0])));
}

// GRU gate pre-activations: gx[g,b], gh[g,b]; also zeroes pg_acc.
__global__ __launch_bounds__(256) void k_gates(const float* __restrict__ emb,
                                               const float* __restrict__ wgt,
                                               const float* __restrict__ h1,
                                               const float* __restrict__ W_ih,
                                               const float* __restrict__ W_hh,
                                               const float* __restrict__ b_ih,
                                               const float* __restrict__ b_hh,
                                               float* __restrict__ gx, float* __restrict__ gh,
                                               float* __restrict__ pg_acc) {
  int idx = blockIdx.x * 256 + threadIdx.x;
  if (idx < B_) pg_acc[idx] = 0.f;
  int b = idx & (B_ - 1);
  int g = idx >> 7;
  if (g >= G3_) return;
  const float4* wr = (const float4*)(W_ih + (size_t)g * KIN_);
  const float4* xe = (const float4*)(emb + b * EMB_);
  const float4* xw = (const float4*)(wgt + b * ENC_);
  float accx = b_ih[g];
  #pragma unroll 8
  for (int k = 0; k < EMB_ / 4; ++k) accx += dot4(wr[k], xe[k]);
  #pragma unroll 8
  for (int k = 0; k < ENC_ / 4; ++k) accx += dot4(wr[EMB_ / 4 + k], xw[k]);
  const float4* wh = (const float4*)(W_hh + (size_t)g * DEC_);
  const float4* xh = (const float4*)(h1 + b * DEC_);
  float acch = b_hh[g];
  #pragma unroll 5
  for (int k = 0; k < DEC_ / 4; ++k) acch += dot4(wh[k], xh[k]);
  gx[g * B_ + b] = accx;
  gh[g * B_ + b] = acch;
}

// GRU combine: h -> hn (f32), hwb bf16 [b,0:300], d_out tail, p_gen partial (h part).
__global__ __launch_bounds__(256) void k_gru_combine(const float* __restrict__ gx,
                                                     const float* __restrict__ gh,
                                                     const float* __restrict__ h1,
                                                     float* __restrict__ hn,
                                                     short* __restrict__ hwb,
                                                     float* __restrict__ outh,
                                                     const float* __restrict__ W_p,
                                                     float* __restrict__ pg_acc) {
  int j = blockIdx.x * 256 + threadIdx.x;
  int b = blockIdx.y;
  __shared__ float red[256];
  float pp = 0.f;
  if (j < DEC_) {
    float xr = gx[j * B_ + b], xz = gx[(j + DEC_) * B_ + b], xn = gx[(j + 2 * DEC_) * B_ + b];
    float hr = gh[j * B_ + b], hz = gh[(j + DEC_) * B_ + b], hnn = gh[(j + 2 * DEC_) * B_ + b];
    float r = 1.f / (1.f + __expf(-(xr + hr)));
    float z = 1.f / (1.f + __expf(-(xz + hz)));
    float n = tanhf(xn + r * hnn);
    float h = (1.f - z) * n + z * h1[b * DEC_ + j];
    hn[b * DEC_ + j] = h;
    hwb[(size_t)b * KHWP_ + j] = f2bf(h);
    outh[b * DEC_ + j] = h;
    pp = h * W_p[j];
  }
  red[threadIdx.x] = pp;
  __syncthreads();
  for (int st = 128; st > 0; st >>= 1) {
    if (threadIdx.x < st) red[threadIdx.x] += red[threadIdx.x + st];
    __syncthreads();
  }
  if (threadIdx.x == 0) atomicAdd(pg_acc + b, red[0]);
}

// logits = hwb . W_out^T + b_out via MFMA; per-tile (max, sumexp) partials.
// PIPELINE FIX (r10): next-chunk loads are issued AFTER the second barrier, inside
// the compute phase. Previous structure issued them BETWEEN the barriers, and the
// compiler's mandatory `s_waitcnt vmcnt(0)` before s_barrier drained them on the
// spot -> zero overlap (r4 160us == r9 157us). Now they drain at the NEXT chunk's
// first barrier, after ~700cy of compute has covered most of the ~900cy HBM latency.
__global__ __launch_bounds__(256) void k_outproj(const short* __restrict__ A,
                                                 const float* __restrict__ Wo,
                                                 const float* __restrict__ bo,
                                                 float* __restrict__ out,
                                                 float* __restrict__ pml) {
  __shared__ __align__(16) short A_lds[B_ * ALDS_STRIDE_];  // 51200 B = 3 blocks/CU
  int tid = threadIdx.x;
  int wave = tid >> 6, lane = tid & 63;
  int r16 = lane & 15, kg = lane >> 4;
  int vcol = blockIdx.x * 64 + wave * 16 + r16;
  int vload = vcol < VOCAB_ ? vcol : VOCAB_ - 1;
  const float* brow = Wo + (size_t)vload * KHW_ + kg * 8;
  f32x4 acc[8];
  #pragma unroll
  for (int mi = 0; mi < 8; ++mi) acc[mi] = (f32x4){0.f, 0.f, 0.f, 0.f};

  short8 ar[12];
  float4 br[2][12];
  float  tl[8];

  #pragma unroll
  for (int i = 0; i < 12; ++i) {
    int g = tid + i * 256, row = g / 24, c8 = g % 24;
    ar[i] = *(const short8*)(A + (size_t)row * KHWP_ + c8 * 8);
  }
  #pragma unroll
  for (int s = 0; s < 6; ++s) {
    br[0][2 * s]     = *(const float4*)(brow + s * 32);
    br[0][2 * s + 1] = *(const float4*)(brow + s * 32 + 4);
  }

  #pragma unroll
  for (int c = 0; c < 7; ++c) {
    __syncthreads();  // previous chunk's A_lds reads complete (drains prev prefetch too)
    #pragma unroll
    for (int i = 0; i < 12; ++i) {
      int g = tid + i * 256, row = g / 24, c8 = g % 24;
      *(short8*)(&A_lds[row * ALDS_STRIDE_ + c8 * 8]) = ar[i];
    }
    __syncthreads();  // staged A visible
    // Issue next-chunk loads NOW (after the barrier): they stay in flight across
    // the whole compute phase below and are only drained at the next barrier.
    if (c < 6) {
      #pragma unroll
      for (int i = 0; i < 12; ++i) {
        int g = tid + i * 256, row = g / 24, c8 = g % 24;
        ar[i] = *(const short8*)(A + (size_t)row * KHWP_ + (c + 1) * CHK_ + c8 * 8);
      }
      if (c + 1 < 6) {
        #pragma unroll
        for (int s = 0; s < 6; ++s) {
          br[(c + 1) & 1][2 * s]     = *(const float4*)(brow + (c + 1) * CHK_ + s * 32);
          br[(c + 1) & 1][2 * s + 1] = *(const float4*)(brow + (c + 1) * CHK_ + s * 32 + 4);
        }
      } else {  // c+1 == 6 -> br[0]; steps 0..4 full, step 5 masked scalars
        #pragma unroll
        for (int s = 0; s < 5; ++s) {
          br[0][2 * s]     = *(const float4*)(brow + 6 * CHK_ + s * 32);
          br[0][2 * s + 1] = *(const float4*)(brow + 6 * CHK_ + s * 32 + 4);
        }
        #pragma unroll
        for (int j = 0; j < 8; ++j)
          tl[j] = (kg * 8 + j < KHW_ - 1312) ? brow[1312 + j] : 0.f;
      }
    }
    // compute chunk c (uses br[c&1] loaded a full chunk ago; LDS reads of A(c))
    #pragma unroll
    for (int s = 0; s < 6; ++s) {
      short8 bf;
      if (c == 6 && s == 5) {
        #pragma unroll
        for (int j = 0; j < 8; ++j) bf[j] = f2bf(tl[j]);
      } else {
        float4 b0 = br[c & 1][2 * s], b1 = br[c & 1][2 * s + 1];
        bf[0] = f2bf(b0.x); bf[1] = f2bf(b0.y); bf[2] = f2bf(b0.z); bf[3] = f2bf(b0.w);
        bf[4] = f2bf(b1.x); bf[5] = f2bf(b1.y); bf[6] = f2bf(b1.z); bf[7] = f2bf(b1.w);
      }
      #pragma unroll
      for (int mi = 0; mi < 8; ++mi) {
        short8 af = *(const short8*)(&A_lds[(mi * 16 + r16) * ALDS_STRIDE_ + s * 32 + kg * 8]);
        acc[mi] = __builtin_amdgcn_mfma_f32_16x16x32_bf16(af, bf, acc[mi], 0, 0, 0);
      }
    }
  }

  __syncthreads();  // drain all A_lds reads; staging buffer now dead -> reuse for stats
  float* wml = (float*)A_lds;  // [4][B_][2] floats = 4096 B, aliased into 51200 B

  bool valid = vcol < VOCAB_;
  float biasv = bo[vload];
  #pragma unroll
  for (int mi = 0; mi < 8; ++mi) {
    #pragma unroll
    for (int j = 0; j < 4; ++j) {
      float lv = valid ? acc[mi][j] + biasv : -INFINITY;
      if (valid) out[(size_t)(mi * 16 + kg * 4 + j) * OUTW_ + vcol] = lv;
      float mr = lv;
      #pragma unroll
      for (int msk = 1; msk < 16; msk <<= 1) mr = fmaxf(mr, __shfl_xor(mr, msk));
      float se = valid ? __expf(lv - mr) : 0.f;
      #pragma unroll
      for (int msk = 1; msk < 16; msk <<= 1) se += __shfl_xor(se, msk);
      if (r16 == 0) {
        wml[(wave * B_ + mi * 16 + kg * 4 + j) * 2]     = mr;
        wml[(wave * B_ + mi * 16 + kg * 4 + j) * 2 + 1] = se;
      }
    }
  }
  __syncthreads();
  if (tid < B_) {
    float M = -INFINITY;
    #pragma unroll
    for (int w = 0; w < 4; ++w) M = fmaxf(M, wml[(w * B_ + tid) * 2]);
    float L = 0.f;
    #pragma unroll
    for (int w = 0; w < 4; ++w) {
      float lw = wml[(w * B_ + tid) * 2 + 1];
      if (lw > 0.f) L += lw * __expf(wml[(w * B_ + tid) * 2] - M);
    }
    pml[((size_t)blockIdx.x * B_ + tid) * 2]     = M;
    pml[((size_t)blockIdx.x * B_ + tid) * 2 + 1] = L;
  }
}

// Merge tile partials -> global (M,L); scale vocab region; zero OOV. 4 blocks per b.
__global__ __launch_bounds__(256) void k_vfinal(float* __restrict__ out,
                                                const float* __restrict__ pml,
                                                const float* __restrict__ pg,
                                                float* __restrict__ mlv) {
  int bq = blockIdx.x, b = blockIdx.y, t = threadIdx.x;
  __shared__ float rm[256], rl[256];
  float lm = -INFINITY, ll = 0.f;
  for (int tile = t; tile < NTILE_; tile += 256) {
    float m = pml[((size_t)tile * B_ + b) * 2];
    float l = pml[((size_t)tile * B_ + b) * 2 + 1];
    float M = fmaxf(lm, m);
    float nl = 0.f;
    if (ll > 0.f) nl += ll * __expf(lm - M);
    if (l > 0.f) nl += l * __expf(m - M);
    lm = M; ll = nl;
  }
  rm[t] = lm; rl[t] = ll;
  __syncthreads();
  for (int st = 128; st > 0; st >>= 1) {
    if (t < st) {
      float m1 = rm[t], l1 = rl[t], m2 = rm[t + st], l2 = rl[t + st];
      float M = fmaxf(m1, m2);
      float L = (l1 > 0.f ? l1 * __expf(m1 - M) : 0.f) + (l2 > 0.f ? l2 * __expf(m2 - M) : 0.f);
      rm[t] = M; rl[t] = L;
    }
    __syncthreads();
  }
  float M = rm[0], L = rl[0];
  float scale = pg[b] / L;
  float* row = out + (size_t)b * OUTW_;
  int lo = bq * 12513;
  int hi = min(lo + 12513, OUTW_);
  for (int v = lo + t; v < hi; v += 256)
    row[v] = (v < VOCAB_) ? scale * __expf(row[v] - M) : 0.f;
  if (bq == 0 && t == 0) { mlv[b * 2] = M; mlv[b * 2 + 1] = L; }
}

// Copy-mechanism scatter (after vfinal): p_out[b, src] += (1-pg)*a2
__global__ __launch_bounds__(256) void k_scatter2(float* __restrict__ out,
                                                  const int* __restrict__ src,
                                                  const float* __restrict__ scores,
                                                  const float* __restrict__ ml2,
                                                  const float* __restrict__ pg) {
  int b = blockIdx.x, t = threadIdx.x;
  float M2 = ml2[b * 2], L2 = ml2[b * 2 + 1];
  float q = (1.f - pg[b]) / L2;
  float* row = out + (size_t)b * OUTW_;
  for (int s = t; s < S_; s += 256) {
    float val = q * __expf(scores[b * S_ + s] - M2);
    atomicAdd(row + src[b * S_ + s], val);
  }
}

extern "C" void kernel_launch(void* const* d_in, const int* in_sizes, int n_in,
                              void* d_out, int out_size, void* d_ws, size_t ws_size,
                              hipStream_t stream) {
  const float* embedded = (const float*)d_in[0];
  const float* enc      = (const float*)d_in[1];
  const float* h1       = (const float*)d_in[2];
  const int*   src      = (const int*)d_in[5];
  const float* W1       = (const float*)d_in[6];
  const float* W2       = (const float*)d_in[7];
  const float* W_ih     = (const float*)d_in[8];
  const float* W_hh     = (const float*)d_in[9];
  const float* b_ih     = (const float*)d_in[10];
  const float* b_hh     = (const float*)d_in[11];
  const float* W_out    = (const float*)d_in[12];
  const float* b_out    = (const float*)d_in[13];
  const float* W_p      = (const float*)d_in[14];
  const float* b_p      = (const float*)d_in[15];
  float* out = (float*)d_out;
  float* ws  = (float*)d_ws;

  // Workspace (cumulative, no overlaps; ~21 MB total, ws is ~1 GB)
  size_t off = 0;
  float* v_ws    = ws + off; off += (size_t)B_ * ENC_;      // 131072
  float* w1_ws   = ws + off; off += (size_t)B_ * ENC_;      // 131072
  float* gx_ws   = ws + off; off += (size_t)G3_ * B_;       // 115200
  float* gh_ws   = ws + off; off += (size_t)G3_ * B_;       // 115200
  float* hn_ws   = ws + off; off += (size_t)B_ * DEC_;      // 38400
  float* sc_ws   = ws + off; off += (size_t)B_ * S_;        // 51200
  float* ml2_ws  = ws + off; off += 256;
  float* pg_ws   = ws + off; off += 128;
  float* pga_ws  = ws + off; off += 128;
  float* mlv_ws  = ws + off; off += 256;
  float* pml_ws  = ws + off; off += (size_t)NTILE_ * B_ * 2; // 200192
  short* hwb_ws  = (short*)(ws + off); off += (size_t)B_ * KHWP_ / 2;  // 86016
  float* part_ws = ws + off;                                 // B*NS*4*PSTRIDE

  int NS = 8;
  while (NS > 1 && (off + (size_t)B_ * NS * 4 * PSTRIDE_) * 4 > ws_size) NS >>= 1;

  // attention 1 -> w1 (flash, one enc sweep)
  k_compute_v<<<B_, 256, 0, stream>>>(W1, h1, v_ws);
  k_attn_pass<<<dim3(B_, NS), 256, 0, stream>>>(enc, v_ws, sc_ws, part_ws, NS);
  k_attn_merge1<<<B_, 256, 0, stream>>>(part_ws, NS * 4, w1_ws);
  // GRU -> h_new (hn f32; hwb bf16 h-part; d_out tail; pg h-partial)
  k_gates<<<(G3_ * B_) / 256, 256, 0, stream>>>(embedded, w1_ws, h1, W_ih, W_hh, b_ih, b_hh,
                                                gx_ws, gh_ws, pga_ws);
  k_gru_combine<<<dim3(2, B_), 256, 0, stream>>>(gx_ws, gh_ws, h1, hn_ws, hwb_ws,
                                                 out + (size_t)B_ * OUTW_, W_p, pga_ws);
  // attention 2 -> hwb w2-part, ml2, p_gen finished
  k_compute_v<<<B_, 256, 0, stream>>>(W2, hn_ws, v_ws);
  k_attn_pass<<<dim3(B_, NS), 256, 0, stream>>>(enc, v_ws, sc_ws, part_ws, NS);
  k_attn_merge2<<<B_, 256, 0, stream>>>(part_ws, NS * 4, hwb_ws, ml2_ws, W_p, b_p,
                                        pga_ws, pg_ws);
  // vocab projection (+ per-tile softmax partials), merge+scale, scatter
  k_outproj<<<NTILE_, 256, 0, stream>>>(hwb_ws, W_out, b_out, out, pml_ws);
  k_vfinal<<<dim3(4, B_), 256, 0, stream>>>(out, pml_ws, pg_ws, mlv_ws);
  k_scatter2<<<B_, 256, 0, stream>>>(out, src, sc_ws, ml2_ws, pg_ws);
}

// Round 11
// 450.066 us; speedup vs baseline: 1.1723x; 1.0553x over previous
//
#include <hip/hip_runtime.h>
#include <stdint.h>

constexpr int B_     = 128;
constexpr int S_     = 400;
constexpr int EMB_   = 128;
constexpr int ENC_   = 1024;
constexpr int DEC_   = 300;
constexpr int VOCAB_ = 50000;
constexpr int OOV_   = 50;
constexpr int OUTW_  = VOCAB_ + OOV_;   // 50050
constexpr int KHW_   = ENC_ + DEC_;     // 1324
constexpr int KHWP_  = 1344;            // 7*192, zero-padded K for MFMA
constexpr int G3_    = 3 * DEC_;        // 900
constexpr int KIN_   = EMB_ + ENC_;     // 1152
constexpr int CHK_   = 192;             // K-chunk staged in LDS (outproj)
constexpr int PSTRIDE_ = 1028;          // flash partial: 1024 wa + m + l (+pad)
constexpr int NTILE_ = 782;             // outproj col tiles (64 each)

typedef __attribute__((ext_vector_type(4))) float f32x4;
typedef __attribute__((ext_vector_type(8))) short short8;

__device__ __forceinline__ float dot4(float4 a, float4 b) {
  return a.x * b.x + a.y * b.y + a.z * b.z + a.w * b.w;
}

__device__ __forceinline__ short f2bf(float f) {  // RNE f32 -> bf16
  uint32_t u = __builtin_bit_cast(uint32_t, f);
  u += 0x7fffu + ((u >> 16) & 1u);
  return (short)(u >> 16);
}

// v[b,e] = sum_d W[e,d] * h[b,d]
__global__ __launch_bounds__(256) void k_compute_v(const float* __restrict__ W,
                                                   const float* __restrict__ h,
                                                   float* __restrict__ v) {
  int b = blockIdx.x;
  __shared__ __align__(16) float hs[DEC_];
  for (int d = threadIdx.x; d < DEC_; d += 256) hs[d] = h[b * DEC_ + d];
  __syncthreads();
  for (int e = threadIdx.x; e < ENC_; e += 256) {
    const float4* w4 = (const float4*)(W + (size_t)e * DEC_);
    const float4* h4 = (const float4*)hs;
    float acc = 0.f;
    #pragma unroll 5
    for (int d = 0; d < DEC_ / 4; ++d) acc += dot4(w4[d], h4[d]);
    v[b * ENC_ + e] = acc;
  }
}

// Flash pass, 2-row ILP: scores + online softmax-weighted enc sum; per-wave partials.
__global__ __launch_bounds__(256) void k_attn_pass(const float* __restrict__ enc,
                                                   const float* __restrict__ v,
                                                   float* __restrict__ scores,
                                                   float* __restrict__ part, int nsplit) {
  int b = blockIdx.x, split = blockIdx.y;
  int wave = threadIdx.x >> 6, lane = threadIdx.x & 63;
  float4 vr[4];
  #pragma unroll
  for (int c = 0; c < 4; ++c) vr[c] = *(const float4*)(v + b * ENC_ + c * 256 + lane * 4);
  float m = -INFINITY, l = 0.f;
  float4 wa[4];
  #pragma unroll
  for (int c = 0; c < 4; ++c) wa[c] = make_float4(0.f, 0.f, 0.f, 0.f);
  int rows = S_ / nsplit, s0 = split * rows, s_end = s0 + rows;
  int s = s0 + wave;
  for (; s + 4 < s_end; s += 8) {
    const float* era = enc + ((size_t)b * S_ + s) * ENC_;
    const float* erb = enc + ((size_t)b * S_ + s + 4) * ENC_;
    float4 e4a[4], e4b[4];
    #pragma unroll
    for (int c = 0; c < 4; ++c) {
      e4a[c] = *(const float4*)(era + c * 256 + lane * 4);
      e4b[c] = *(const float4*)(erb + c * 256 + lane * 4);
    }
    float pa = 0.f, pb = 0.f;
    #pragma unroll
    for (int c = 0; c < 4; ++c) { pa += dot4(e4a[c], vr[c]); pb += dot4(e4b[c], vr[c]); }
    #pragma unroll
    for (int off = 32; off; off >>= 1) {
      pa += __shfl_xor(pa, off);
      pb += __shfl_xor(pb, off);
    }
    if (lane == 0) { scores[b * S_ + s] = pa; scores[b * S_ + s + 4] = pb; }
    float nm = fmaxf(m, fmaxf(pa, pb));
    float sc = __expf(m - nm);
    float ea = __expf(pa - nm);
    float eb = __expf(pb - nm);
    l = l * sc + ea + eb;
    #pragma unroll
    for (int c = 0; c < 4; ++c) {
      wa[c].x = wa[c].x * sc + ea * e4a[c].x + eb * e4b[c].x;
      wa[c].y = wa[c].y * sc + ea * e4a[c].y + eb * e4b[c].y;
      wa[c].z = wa[c].z * sc + ea * e4a[c].z + eb * e4b[c].z;
      wa[c].w = wa[c].w * sc + ea * e4a[c].w + eb * e4b[c].w;
    }
    m = nm;
  }
  if (s < s_end) {  // tail single row
    const float* er = enc + ((size_t)b * S_ + s) * ENC_;
    float4 e4[4];
    #pragma unroll
    for (int c = 0; c < 4; ++c) e4[c] = *(const float4*)(er + c * 256 + lane * 4);
    float p = 0.f;
    #pragma unroll
    for (int c = 0; c < 4; ++c) p += dot4(e4[c], vr[c]);
    #pragma unroll
    for (int off = 32; off; off >>= 1) p += __shfl_xor(p, off);
    if (lane == 0) scores[b * S_ + s] = p;
    float nm = fmaxf(m, p);
    float sc = __expf(m - nm), pe = __expf(p - nm);
    l = l * sc + pe;
    #pragma unroll
    for (int c = 0; c < 4; ++c) {
      wa[c].x = wa[c].x * sc + pe * e4[c].x;
      wa[c].y = wa[c].y * sc + pe * e4[c].y;
      wa[c].z = wa[c].z * sc + pe * e4[c].z;
      wa[c].w = wa[c].w * sc + pe * e4[c].w;
    }
    m = nm;
  }
  float* pp = part + ((size_t)b * (nsplit * 4) + split * 4 + wave) * PSTRIDE_;
  #pragma unroll
  for (int c = 0; c < 4; ++c) *(float4*)(pp + c * 256 + lane * 4) = wa[c];
  if (lane == 0) { pp[1024] = m; pp[1025] = l; }
}

// Merge partials -> w1[b,:] (f32) for GRU input
__global__ __launch_bounds__(256) void k_attn_merge1(const float* __restrict__ part, int P,
                                                     float* __restrict__ wout) {
  int b = blockIdx.x, tid = threadIdx.x;
  const float* pb = part + (size_t)b * P * PSTRIDE_;
  __shared__ float scl[32];
  __shared__ float Ls;
  if (tid == 0) {
    float M = -INFINITY;
    for (int p = 0; p < P; ++p) M = fmaxf(M, pb[p * PSTRIDE_ + 1024]);
    float L = 0.f;
    for (int p = 0; p < P; ++p) {
      float lp = pb[p * PSTRIDE_ + 1025];
      float e = (lp > 0.f) ? __expf(pb[p * PSTRIDE_ + 1024] - M) : 0.f;
      scl[p] = e;
      L += lp * e;
    }
    Ls = L;
  }
  __syncthreads();
  float invL = 1.f / Ls;
  for (int e = tid; e < ENC_; e += 256) {
    float acc = 0.f;
    for (int p = 0; p < P; ++p) acc += scl[p] * pb[p * PSTRIDE_ + e];
    wout[(size_t)b * ENC_ + e] = acc * invL;
  }
}

// Merge partials (attn2) -> hwb bf16 [b,300:1324], ml2, and finish p_gen.
__global__ __launch_bounds__(256) void k_attn_merge2(const float* __restrict__ part, int P,
                                                     short* __restrict__ hwb,
                                                     float* __restrict__ ml,
                                                     const float* __restrict__ W_p,
                                                     const float* __restrict__ b_p,
                                                     const float* __restrict__ pg_acc,
                                                     float* __restrict__ pg) {
  int b = blockIdx.x, tid = threadIdx.x;
  const float* pb = part + (size_t)b * P * PSTRIDE_;
  __shared__ float scl[32];
  __shared__ float Ls;
  __shared__ float red[256];
  if (tid == 0) {
    float M = -INFINITY;
    for (int p = 0; p < P; ++p) M = fmaxf(M, pb[p * PSTRIDE_ + 1024]);
    float L = 0.f;
    for (int p = 0; p < P; ++p) {
      float lp = pb[p * PSTRIDE_ + 1025];
      float e = (lp > 0.f) ? __expf(pb[p * PSTRIDE_ + 1024] - M) : 0.f;
      scl[p] = e;
      L += lp * e;
    }
    Ls = L;
    ml[b * 2] = M; ml[b * 2 + 1] = L;
  }
  __syncthreads();
  float invL = 1.f / Ls;
  float pacc = 0.f;
  for (int e = tid; e < ENC_; e += 256) {
    float acc = 0.f;
    for (int p = 0; p < P; ++p) acc += scl[p] * pb[p * PSTRIDE_ + e];
    float w = acc * invL;
    hwb[(size_t)b * KHWP_ + DEC_ + e] = f2bf(w);
    pacc += w * W_p[DEC_ + e];
  }
  if (tid < KHWP_ - KHW_) hwb[(size_t)b * KHWP_ + KHW_ + tid] = 0;  // zero pad
  red[tid] = pacc;
  __syncthreads();
  for (int st = 128; st > 0; st >>= 1) {
    if (tid < st) red[tid] += red[tid + st];
    __syncthreads();
  }
  if (tid == 0) pg[b] = 1.f / (1.f + __expf(-(red[0] + pg_acc[b] + b_p[0])));
}

// GRU gate pre-activations: gx[g,b], gh[g,b]; also zeroes pg_acc.
__global__ __launch_bounds__(256) void k_gates(const float* __restrict__ emb,
                                               const float* __restrict__ wgt,
                                               const float* __restrict__ h1,
                                               const float* __restrict__ W_ih,
                                               const float* __restrict__ W_hh,
                                               const float* __restrict__ b_ih,
                                               const float* __restrict__ b_hh,
                                               float* __restrict__ gx, float* __restrict__ gh,
                                               float* __restrict__ pg_acc) {
  int idx = blockIdx.x * 256 + threadIdx.x;
  if (idx < B_) pg_acc[idx] = 0.f;
  int b = idx & (B_ - 1);
  int g = idx >> 7;
  if (g >= G3_) return;
  const float4* wr = (const float4*)(W_ih + (size_t)g * KIN_);
  const float4* xe = (const float4*)(emb + b * EMB_);
  const float4* xw = (const float4*)(wgt + b * ENC_);
  float accx = b_ih[g];
  #pragma unroll 8
  for (int k = 0; k < EMB_ / 4; ++k) accx += dot4(wr[k], xe[k]);
  #pragma unroll 8
  for (int k = 0; k < ENC_ / 4; ++k) accx += dot4(wr[EMB_ / 4 + k], xw[k]);
  const float4* wh = (const float4*)(W_hh + (size_t)g * DEC_);
  const float4* xh = (const float4*)(h1 + b * DEC_);
  float acch = b_hh[g];
  #pragma unroll 5
  for (int k = 0; k < DEC_ / 4; ++k) acch += dot4(wh[k], xh[k]);
  gx[g * B_ + b] = accx;
  gh[g * B_ + b] = acch;
}

// GRU combine: h -> hn (f32), hwb bf16 [b,0:300], d_out tail, p_gen partial (h part).
__global__ __launch_bounds__(256) void k_gru_combine(const float* __restrict__ gx,
                                                     const float* __restrict__ gh,
                                                     const float* __restrict__ h1,
                                                     float* __restrict__ hn,
                                                     short* __restrict__ hwb,
                                                     float* __restrict__ outh,
                                                     const float* __restrict__ W_p,
                                                     float* __restrict__ pg_acc) {
  int j = blockIdx.x * 256 + threadIdx.x;
  int b = blockIdx.y;
  __shared__ float red[256];
  float pp = 0.f;
  if (j < DEC_) {
    float xr = gx[j * B_ + b], xz = gx[(j + DEC_) * B_ + b], xn = gx[(j + 2 * DEC_) * B_ + b];
    float hr = gh[j * B_ + b], hz = gh[(j + DEC_) * B_ + b], hnn = gh[(j + 2 * DEC_) * B_ + b];
    float r = 1.f / (1.f + __expf(-(xr + hr)));
    float z = 1.f / (1.f + __expf(-(xz + hz)));
    float n = tanhf(xn + r * hnn);
    float h = (1.f - z) * n + z * h1[b * DEC_ + j];
    hn[b * DEC_ + j] = h;
    hwb[(size_t)b * KHWP_ + j] = f2bf(h);
    outh[b * DEC_ + j] = h;
    pp = h * W_p[j];
  }
  red[threadIdx.x] = pp;
  __syncthreads();
  for (int st = 128; st > 0; st >>= 1) {
    if (threadIdx.x < st) red[threadIdx.x] += red[threadIdx.x + st];
    __syncthreads();
  }
  if (threadIdx.x == 0) atomicAdd(pg_acc + b, red[0]);
}

// logits = hwb . W_out^T + b_out via MFMA; per-tile (max, sumexp) partials.
// r11: A staged via global_load_lds (width 16) -> frees the ar[12]=48-VGPR staging
// buffer that was blowing the live-register budget (~200 live vs 132 alloc) and
// forcing the compiler to sink the B prefetch (r4/r9/r10 all ~140-160us).
// LDS layout: unpadded [128][192] bf16 with XOR swizzle byte^((row&7)<<4) applied
// via the PRE-SWIZZLED GLOBAL SOURCE address (rule #21: gload_lds dest is linear)
// and the same XOR on ds_read -> ~2-way bank conflicts.
__global__ __launch_bounds__(256) void k_outproj(const short* __restrict__ A,
                                                 const float* __restrict__ Wo,
                                                 const float* __restrict__ bo,
                                                 float* __restrict__ out,
                                                 float* __restrict__ pml) {
  __shared__ __align__(16) short A_lds[B_ * CHK_];  // 49152 B = 3 blocks/CU
  int tid = threadIdx.x;
  int wave = tid >> 6, lane = tid & 63;
  int r16 = lane & 15, kg = lane >> 4;
  int vcol = blockIdx.x * 64 + wave * 16 + r16;
  int vload = vcol < VOCAB_ ? vcol : VOCAB_ - 1;
  const float* brow = Wo + (size_t)vload * KHW_ + kg * 8;
  f32x4 acc[8];
  #pragma unroll
  for (int mi = 0; mi < 8; ++mi) acc[mi] = (f32x4){0.f, 0.f, 0.f, 0.f};

  // Pre-swizzled per-granule source offsets (granule g = tid + i*256, 16B each).
  // LDS linear dest byte D = g*16; row = D/384, p = D%384; source byte within the
  // row's chunk window = p ^ ((row&7)<<4). 12 u32 offsets, invariant over chunks.
  const char* A8 = (const char*)A;
  uint32_t srcoff[12];
  #pragma unroll
  for (int i = 0; i < 12; ++i) {
    int g = tid + i * 256;
    int row = g / 24;                // 24 granules (16B) per 384B row
    int p = (g - row * 24) * 16;
    srcoff[i] = (uint32_t)(row * 2688 + (p ^ ((row & 7) << 4)));  // 2688 = KHWP*2
  }

  float4 br[2][12];  // B double-buffer (static-indexed under full unroll)
  float  tl[8];      // masked tail (k0=1312) scalars

  // prologue: issue A(0) direct-to-LDS and B(0)
  #pragma unroll
  for (int i = 0; i < 12; ++i) {
    __builtin_amdgcn_global_load_lds(
        (const __attribute__((address_space(1))) void*)(A8 + srcoff[i]),
        (__attribute__((address_space(3))) void*)((char*)A_lds + i * 4096 + wave * 1024),
        16, 0, 0);
  }
  #pragma unroll
  for (int s = 0; s < 6; ++s) {
    br[0][2 * s]     = *(const float4*)(brow + s * 32);
    br[0][2 * s + 1] = *(const float4*)(brow + s * 32 + 4);
  }

  int swzl = (r16 & 7) << 4;
  const char* lbase = (const char*)A_lds + r16 * 384;

  #pragma unroll
  for (int c = 0; c < 7; ++c) {
    __syncthreads();  // drains gload A(c) + br(c); LDS(c) ready
    // issue next-chunk B now: flies across the whole compute phase
    if (c < 6) {
      if (c + 1 < 6) {
        #pragma unroll
        for (int s = 0; s < 6; ++s) {
          br[(c + 1) & 1][2 * s]     = *(const float4*)(brow + (c + 1) * CHK_ + s * 32);
          br[(c + 1) & 1][2 * s + 1] = *(const float4*)(brow + (c + 1) * CHK_ + s * 32 + 4);
        }
      } else {  // c+1 == 6 -> br[0]; steps 0..4 full, step 5 masked scalars
        #pragma unroll
        for (int s = 0; s < 5; ++s) {
          br[0][2 * s]     = *(const float4*)(brow + 6 * CHK_ + s * 32);
          br[0][2 * s + 1] = *(const float4*)(brow + 6 * CHK_ + s * 32 + 4);
        }
        #pragma unroll
        for (int j = 0; j < 8; ++j)
          tl[j] = (kg * 8 + j < KHW_ - 1312) ? brow[1312 + j] : 0.f;
      }
    }
    // compute chunk c: swizzled ds_read + MFMA, B from regs loaded a chunk ago
    #pragma unroll
    for (int s = 0; s < 6; ++s) {
      short8 bf;
      if (c == 6 && s == 5) {
        #pragma unroll
        for (int j = 0; j < 8; ++j) bf[j] = f2bf(tl[j]);
      } else {
        float4 b0 = br[c & 1][2 * s], b1 = br[c & 1][2 * s + 1];
        bf[0] = f2bf(b0.x); bf[1] = f2bf(b0.y); bf[2] = f2bf(b0.z); bf[3] = f2bf(b0.w);
        bf[4] = f2bf(b1.x); bf[5] = f2bf(b1.y); bf[6] = f2bf(b1.z); bf[7] = f2bf(b1.w);
      }
      int q = (s * 64 + kg * 16) ^ swzl;
      #pragma unroll
      for (int mi = 0; mi < 8; ++mi) {
        short8 af = *(const short8*)(lbase + mi * 6144 + q);
        acc[mi] = __builtin_amdgcn_mfma_f32_16x16x32_bf16(af, bf, acc[mi], 0, 0, 0);
      }
    }
    __syncthreads();  // LDS reads of chunk c done
    if (c < 6) {      // issue A(c+1) direct-to-LDS (L2-hot, ~300cy, drains at next top)
      #pragma unroll
      for (int i = 0; i < 12; ++i) {
        __builtin_amdgcn_global_load_lds(
            (const __attribute__((address_space(1))) void*)(A8 + srcoff[i] + (c + 1) * 384),
            (__attribute__((address_space(3))) void*)((char*)A_lds + i * 4096 + wave * 1024),
            16, 0, 0);
      }
    }
  }

  float* wml = (float*)A_lds;  // staging dead; reuse for [4][B_][2] stats (4 KB)

  bool valid = vcol < VOCAB_;
  float biasv = bo[vload];
  #pragma unroll
  for (int mi = 0; mi < 8; ++mi) {
    #pragma unroll
    for (int j = 0; j < 4; ++j) {
      float lv = valid ? acc[mi][j] + biasv : -INFINITY;
      if (valid) out[(size_t)(mi * 16 + kg * 4 + j) * OUTW_ + vcol] = lv;
      float mr = lv;
      #pragma unroll
      for (int msk = 1; msk < 16; msk <<= 1) mr = fmaxf(mr, __shfl_xor(mr, msk));
      float se = valid ? __expf(lv - mr) : 0.f;
      #pragma unroll
      for (int msk = 1; msk < 16; msk <<= 1) se += __shfl_xor(se, msk);
      if (r16 == 0) {
        wml[(wave * B_ + mi * 16 + kg * 4 + j) * 2]     = mr;
        wml[(wave * B_ + mi * 16 + kg * 4 + j) * 2 + 1] = se;
      }
    }
  }
  __syncthreads();
  if (tid < B_) {
    float M = -INFINITY;
    #pragma unroll
    for (int w = 0; w < 4; ++w) M = fmaxf(M, wml[(w * B_ + tid) * 2]);
    float L = 0.f;
    #pragma unroll
    for (int w = 0; w < 4; ++w) {
      float lw = wml[(w * B_ + tid) * 2 + 1];
      if (lw > 0.f) L += lw * __expf(wml[(w * B_ + tid) * 2] - M);
    }
    pml[((size_t)blockIdx.x * B_ + tid) * 2]     = M;
    pml[((size_t)blockIdx.x * B_ + tid) * 2 + 1] = L;
  }
}

// Merge tile partials -> global (M,L); scale vocab region; zero OOV. 4 blocks per b.
__global__ __launch_bounds__(256) void k_vfinal(float* __restrict__ out,
                                                const float* __restrict__ pml,
                                                const float* __restrict__ pg,
                                                float* __restrict__ mlv) {
  int bq = blockIdx.x, b = blockIdx.y, t = threadIdx.x;
  __shared__ float rm[256], rl[256];
  float lm = -INFINITY, ll = 0.f;
  for (int tile = t; tile < NTILE_; tile += 256) {
    float m = pml[((size_t)tile * B_ + b) * 2];
    float l = pml[((size_t)tile * B_ + b) * 2 + 1];
    float M = fmaxf(lm, m);
    float nl = 0.f;
    if (ll > 0.f) nl += ll * __expf(lm - M);
    if (l > 0.f) nl += l * __expf(m - M);
    lm = M; ll = nl;
  }
  rm[t] = lm; rl[t] = ll;
  __syncthreads();
  for (int st = 128; st > 0; st >>= 1) {
    if (t < st) {
      float m1 = rm[t], l1 = rl[t], m2 = rm[t + st], l2 = rl[t + st];
      float M = fmaxf(m1, m2);
      float L = (l1 > 0.f ? l1 * __expf(m1 - M) : 0.f) + (l2 > 0.f ? l2 * __expf(m2 - M) : 0.f);
      rm[t] = M; rl[t] = L;
    }
    __syncthreads();
  }
  float M = rm[0], L = rl[0];
  float scale = pg[b] / L;
  float* row = out + (size_t)b * OUTW_;
  int lo = bq * 12513;
  int hi = min(lo + 12513, OUTW_);
  for (int v = lo + t; v < hi; v += 256)
    row[v] = (v < VOCAB_) ? scale * __expf(row[v] - M) : 0.f;
  if (bq == 0 && t == 0) { mlv[b * 2] = M; mlv[b * 2 + 1] = L; }
}

// Copy-mechanism scatter (after vfinal): p_out[b, src] += (1-pg)*a2
__global__ __launch_bounds__(256) void k_scatter2(float* __restrict__ out,
                                                  const int* __restrict__ src,
                                                  const float* __restrict__ scores,
                                                  const float* __restrict__ ml2,
                                                  const float* __restrict__ pg) {
  int b = blockIdx.x, t = threadIdx.x;
  float M2 = ml2[b * 2], L2 = ml2[b * 2 + 1];
  float q = (1.f - pg[b]) / L2;
  float* row = out + (size_t)b * OUTW_;
  for (int s = t; s < S_; s += 256) {
    float val = q * __expf(scores[b * S_ + s] - M2);
    atomicAdd(row + src[b * S_ + s], val);
  }
}

extern "C" void kernel_launch(void* const* d_in, const int* in_sizes, int n_in,
                              void* d_out, int out_size, void* d_ws, size_t ws_size,
                              hipStream_t stream) {
  const float* embedded = (const float*)d_in[0];
  const float* enc      = (const float*)d_in[1];
  const float* h1       = (const float*)d_in[2];
  const int*   src      = (const int*)d_in[5];
  const float* W1       = (const float*)d_in[6];
  const float* W2       = (const float*)d_in[7];
  const float* W_ih     = (const float*)d_in[8];
  const float* W_hh     = (const float*)d_in[9];
  const float* b_ih     = (const float*)d_in[10];
  const float* b_hh     = (const float*)d_in[11];
  const float* W_out    = (const float*)d_in[12];
  const float* b_out    = (const float*)d_in[13];
  const float* W_p      = (const float*)d_in[14];
  const float* b_p      = (const float*)d_in[15];
  float* out = (float*)d_out;
  float* ws  = (float*)d_ws;

  // Workspace (cumulative, no overlaps; ~21 MB total, ws is ~1 GB)
  size_t off = 0;
  float* v_ws    = ws + off; off += (size_t)B_ * ENC_;      // 131072
  float* w1_ws   = ws + off; off += (size_t)B_ * ENC_;      // 131072
  float* gx_ws   = ws + off; off += (size_t)G3_ * B_;       // 115200
  float* gh_ws   = ws + off; off += (size_t)G3_ * B_;       // 115200
  float* hn_ws   = ws + off; off += (size_t)B_ * DEC_;      // 38400
  float* sc_ws   = ws + off; off += (size_t)B_ * S_;        // 51200
  float* ml2_ws  = ws + off; off += 256;
  float* pg_ws   = ws + off; off += 128;
  float* pga_ws  = ws + off; off += 128;
  float* mlv_ws  = ws + off; off += 256;
  float* pml_ws  = ws + off; off += (size_t)NTILE_ * B_ * 2; // 200192
  short* hwb_ws  = (short*)(ws + off); off += (size_t)B_ * KHWP_ / 2;  // 86016
  float* part_ws = ws + off;                                 // B*NS*4*PSTRIDE

  int NS = 8;
  while (NS > 1 && (off + (size_t)B_ * NS * 4 * PSTRIDE_) * 4 > ws_size) NS >>= 1;

  // attention 1 -> w1 (flash, one enc sweep)
  k_compute_v<<<B_, 256, 0, stream>>>(W1, h1, v_ws);
  k_attn_pass<<<dim3(B_, NS), 256, 0, stream>>>(enc, v_ws, sc_ws, part_ws, NS);
  k_attn_merge1<<<B_, 256, 0, stream>>>(part_ws, NS * 4, w1_ws);
  // GRU -> h_new (hn f32; hwb bf16 h-part; d_out tail; pg h-partial)
  k_gates<<<(G3_ * B_) / 256, 256, 0, stream>>>(embedded, w1_ws, h1, W_ih, W_hh, b_ih, b_hh,
                                                gx_ws, gh_ws, pga_ws);
  k_gru_combine<<<dim3(2, B_), 256, 0, stream>>>(gx_ws, gh_ws, h1, hn_ws, hwb_ws,
                                                 out + (size_t)B_ * OUTW_, W_p, pga_ws);
  // attention 2 -> hwb w2-part, ml2, p_gen finished
  k_compute_v<<<B_, 256, 0, stream>>>(W2, hn_ws, v_ws);
  k_attn_pass<<<dim3(B_, NS), 256, 0, stream>>>(enc, v_ws, sc_ws, part_ws, NS);
  k_attn_merge2<<<B_, 256, 0, stream>>>(part_ws, NS * 4, hwb_ws, ml2_ws, W_p, b_p,
                                        pga_ws, pg_ws);
  // vocab projection (+ per-tile softmax partials), merge+scale, scatter
  k_outproj<<<NTILE_, 256, 0, stream>>>(hwb_ws, W_out, b_out, out, pml_ws);
  k_vfinal<<<dim3(4, B_), 256, 0, stream>>>(out, pml_ws, pg_ws, mlv_ws);
  k_scatter2<<<B_, 256, 0, stream>>>(out, src, sc_ws, ml2_ws, pg_ws);
}

// Round 12
// 443.802 us; speedup vs baseline: 1.1889x; 1.0141x over previous
//
#include <hip/hip_runtime.h>
#include <stdint.h>

constexpr int B_     = 128;
constexpr int S_     = 400;
constexpr int EMB_   = 128;
constexpr int ENC_   = 1024;
constexpr int DEC_   = 300;
constexpr int VOCAB_ = 50000;
constexpr int OOV_   = 50;
constexpr int OUTW_  = VOCAB_ + OOV_;   // 50050
constexpr int KHW_   = ENC_ + DEC_;     // 1324
constexpr int KHWP_  = 1344;            // 14*96, zero-padded K for MFMA
constexpr int G3_    = 3 * DEC_;        // 900
constexpr int KIN_   = EMB_ + ENC_;     // 1152
constexpr int CHK_   = 96;              // K-chunk (bf16) per LDS buffer
constexpr int CHKB_  = 192;             // bytes per row per chunk
constexpr int NC_    = 14;              // 1344 / 96
constexpr int PSTRIDE_ = 1028;          // flash partial: 1024 wa + m + l (+pad)
constexpr int NTILE_ = 782;             // outproj col tiles (64 each)

typedef __attribute__((ext_vector_type(4))) float f32x4;
typedef __attribute__((ext_vector_type(8))) short short8;

__device__ __forceinline__ float dot4(float4 a, float4 b) {
  return a.x * b.x + a.y * b.y + a.z * b.z + a.w * b.w;
}

__device__ __forceinline__ short f2bf(float f) {  // RNE f32 -> bf16
  uint32_t u = __builtin_bit_cast(uint32_t, f);
  u += 0x7fffu + ((u >> 16) & 1u);
  return (short)(u >> 16);
}

// v[b,e] = sum_d W[e,d] * h[b,d]
__global__ __launch_bounds__(256) void k_compute_v(const float* __restrict__ W,
                                                   const float* __restrict__ h,
                                                   float* __restrict__ v) {
  int b = blockIdx.x;
  __shared__ __align__(16) float hs[DEC_];
  for (int d = threadIdx.x; d < DEC_; d += 256) hs[d] = h[b * DEC_ + d];
  __syncthreads();
  for (int e = threadIdx.x; e < ENC_; e += 256) {
    const float4* w4 = (const float4*)(W + (size_t)e * DEC_);
    const float4* h4 = (const float4*)hs;
    float acc = 0.f;
    #pragma unroll 5
    for (int d = 0; d < DEC_ / 4; ++d) acc += dot4(w4[d], h4[d]);
    v[b * ENC_ + e] = acc;
  }
}

// Flash pass, 2-row ILP: scores + online softmax-weighted enc sum; per-wave partials.
__global__ __launch_bounds__(256) void k_attn_pass(const float* __restrict__ enc,
                                                   const float* __restrict__ v,
                                                   float* __restrict__ scores,
                                                   float* __restrict__ part, int nsplit) {
  int b = blockIdx.x, split = blockIdx.y;
  int wave = threadIdx.x >> 6, lane = threadIdx.x & 63;
  float4 vr[4];
  #pragma unroll
  for (int c = 0; c < 4; ++c) vr[c] = *(const float4*)(v + b * ENC_ + c * 256 + lane * 4);
  float m = -INFINITY, l = 0.f;
  float4 wa[4];
  #pragma unroll
  for (int c = 0; c < 4; ++c) wa[c] = make_float4(0.f, 0.f, 0.f, 0.f);
  int rows = S_ / nsplit, s0 = split * rows, s_end = s0 + rows;
  int s = s0 + wave;
  for (; s + 4 < s_end; s += 8) {
    const float* era = enc + ((size_t)b * S_ + s) * ENC_;
    const float* erb = enc + ((size_t)b * S_ + s + 4) * ENC_;
    float4 e4a[4], e4b[4];
    #pragma unroll
    for (int c = 0; c < 4; ++c) {
      e4a[c] = *(const float4*)(era + c * 256 + lane * 4);
      e4b[c] = *(const float4*)(erb + c * 256 + lane * 4);
    }
    float pa = 0.f, pb = 0.f;
    #pragma unroll
    for (int c = 0; c < 4; ++c) { pa += dot4(e4a[c], vr[c]); pb += dot4(e4b[c], vr[c]); }
    #pragma unroll
    for (int off = 32; off; off >>= 1) {
      pa += __shfl_xor(pa, off);
      pb += __shfl_xor(pb, off);
    }
    if (lane == 0) { scores[b * S_ + s] = pa; scores[b * S_ + s + 4] = pb; }
    float nm = fmaxf(m, fmaxf(pa, pb));
    float sc = __expf(m - nm);
    float ea = __expf(pa - nm);
    float eb = __expf(pb - nm);
    l = l * sc + ea + eb;
    #pragma unroll
    for (int c = 0; c < 4; ++c) {
      wa[c].x = wa[c].x * sc + ea * e4a[c].x + eb * e4b[c].x;
      wa[c].y = wa[c].y * sc + ea * e4a[c].y + eb * e4b[c].y;
      wa[c].z = wa[c].z * sc + ea * e4a[c].z + eb * e4b[c].z;
      wa[c].w = wa[c].w * sc + ea * e4a[c].w + eb * e4b[c].w;
    }
    m = nm;
  }
  if (s < s_end) {  // tail single row
    const float* er = enc + ((size_t)b * S_ + s) * ENC_;
    float4 e4[4];
    #pragma unroll
    for (int c = 0; c < 4; ++c) e4[c] = *(const float4*)(er + c * 256 + lane * 4);
    float p = 0.f;
    #pragma unroll
    for (int c = 0; c < 4; ++c) p += dot4(e4[c], vr[c]);
    #pragma unroll
    for (int off = 32; off; off >>= 1) p += __shfl_xor(p, off);
    if (lane == 0) scores[b * S_ + s] = p;
    float nm = fmaxf(m, p);
    float sc = __expf(m - nm), pe = __expf(p - nm);
    l = l * sc + pe;
    #pragma unroll
    for (int c = 0; c < 4; ++c) {
      wa[c].x = wa[c].x * sc + pe * e4[c].x;
      wa[c].y = wa[c].y * sc + pe * e4[c].y;
      wa[c].z = wa[c].z * sc + pe * e4[c].z;
      wa[c].w = wa[c].w * sc + pe * e4[c].w;
    }
    m = nm;
  }
  float* pp = part + ((size_t)b * (nsplit * 4) + split * 4 + wave) * PSTRIDE_;
  #pragma unroll
  for (int c = 0; c < 4; ++c) *(float4*)(pp + c * 256 + lane * 4) = wa[c];
  if (lane == 0) { pp[1024] = m; pp[1025] = l; }
}

// Merge partials -> w1[b,:] (f32) for GRU input
__global__ __launch_bounds__(256) void k_attn_merge1(const float* __restrict__ part, int P,
                                                     float* __restrict__ wout) {
  int b = blockIdx.x, tid = threadIdx.x;
  const float* pb = part + (size_t)b * P * PSTRIDE_;
  __shared__ float scl[32];
  __shared__ float Ls;
  if (tid == 0) {
    float M = -INFINITY;
    for (int p = 0; p < P; ++p) M = fmaxf(M, pb[p * PSTRIDE_ + 1024]);
    float L = 0.f;
    for (int p = 0; p < P; ++p) {
      float lp = pb[p * PSTRIDE_ + 1025];
      float e = (lp > 0.f) ? __expf(pb[p * PSTRIDE_ + 1024] - M) : 0.f;
      scl[p] = e;
      L += lp * e;
    }
    Ls = L;
  }
  __syncthreads();
  float invL = 1.f / Ls;
  for (int e = tid; e < ENC_; e += 256) {
    float acc = 0.f;
    for (int p = 0; p < P; ++p) acc += scl[p] * pb[p * PSTRIDE_ + e];
    wout[(size_t)b * ENC_ + e] = acc * invL;
  }
}

// Merge partials (attn2) -> hwb bf16 [b,300:1324], ml2, and finish p_gen.
__global__ __launch_bounds__(256) void k_attn_merge2(const float* __restrict__ part, int P,
                                                     short* __restrict__ hwb,
                                                     float* __restrict__ ml,
                                                     const float* __restrict__ W_p,
                                                     const float* __restrict__ b_p,
                                                     const float* __restrict__ pg_acc,
                                                     float* __restrict__ pg) {
  int b = blockIdx.x, tid = threadIdx.x;
  const float* pb = part + (size_t)b * P * PSTRIDE_;
  __shared__ float scl[32];
  __shared__ float Ls;
  __shared__ float red[256];
  if (tid == 0) {
    float M = -INFINITY;
    for (int p = 0; p < P; ++p) M = fmaxf(M, pb[p * PSTRIDE_ + 1024]);
    float L = 0.f;
    for (int p = 0; p < P; ++p) {
      float lp = pb[p * PSTRIDE_ + 1025];
      float e = (lp > 0.f) ? __expf(pb[p * PSTRIDE_ + 1024] - M) : 0.f;
      scl[p] = e;
      L += lp * e;
    }
    Ls = L;
    ml[b * 2] = M; ml[b * 2 + 1] = L;
  }
  __syncthreads();
  float invL = 1.f / Ls;
  float pacc = 0.f;
  for (int e = tid; e < ENC_; e += 256) {
    float acc = 0.f;
    for (int p = 0; p < P; ++p) acc += scl[p] * pb[p * PSTRIDE_ + e];
    float w = acc * invL;
    hwb[(size_t)b * KHWP_ + DEC_ + e] = f2bf(w);
    pacc += w * W_p[DEC_ + e];
  }
  if (tid < KHWP_ - KHW_) hwb[(size_t)b * KHWP_ + KHW_ + tid] = 0;  // zero pad
  red[tid] = pacc;
  __syncthreads();
  for (int st = 128; st > 0; st >>= 1) {
    if (tid < st) red[tid] += red[tid + st];
    __syncthreads();
  }
  if (tid == 0) pg[b] = 1.f / (1.f + __expf(-(red[0] + pg_acc[b] + b_p[0])));
}

// GRU gate pre-activations: gx[g,b], gh[g,b]; also zeroes pg_acc.
__global__ __launch_bounds__(256) void k_gates(const float* __restrict__ emb,
                                               const float* __restrict__ wgt,
                                               const float* __restrict__ h1,
                                               const float* __restrict__ W_ih,
                                               const float* __restrict__ W_hh,
                                               const float* __restrict__ b_ih,
                                               const float* __restrict__ b_hh,
                                               float* __restrict__ gx, float* __restrict__ gh,
                                               float* __restrict__ pg_acc) {
  int idx = blockIdx.x * 256 + threadIdx.x;
  if (idx < B_) pg_acc[idx] = 0.f;
  int b = idx & (B_ - 1);
  int g = idx >> 7;
  if (g >= G3_) return;
  const float4* wr = (const float4*)(W_ih + (size_t)g * KIN_);
  const float4* xe = (const float4*)(emb + b * EMB_);
  const float4* xw = (const float4*)(wgt + b * ENC_);
  float accx = b_ih[g];
  #pragma unroll 8
  for (int k = 0; k < EMB_ / 4; ++k) accx += dot4(wr[k], xe[k]);
  #pragma unroll 8
  for (int k = 0; k < ENC_ / 4; ++k) accx += dot4(wr[EMB_ / 4 + k], xw[k]);
  const float4* wh = (const float4*)(W_hh + (size_t)g * DEC_);
  const float4* xh = (const float4*)(h1 + b * DEC_);
  float acch = b_hh[g];
  #pragma unroll 5
  for (int k = 0; k < DEC_ / 4; ++k) acch += dot4(wh[k], xh[k]);
  gx[g * B_ + b] = accx;
  gh[g * B_ + b] = acch;
}

// GRU combine: h -> hn (f32), hwb bf16 [b,0:300], d_out tail, p_gen partial (h part).
__global__ __launch_bounds__(256) void k_gru_combine(const float* __restrict__ gx,
                                                     const float* __restrict__ gh,
                                                     const float* __restrict__ h1,
                                                     float* __restrict__ hn,
                                                     short* __restrict__ hwb,
                                                     float* __restrict__ outh,
                                                     const float* __restrict__ W_p,
                                                     float* __restrict__ pg_acc) {
  int j = blockIdx.x * 256 + threadIdx.x;
  int b = blockIdx.y;
  __shared__ float red[256];
  float pp = 0.f;
  if (j < DEC_) {
    float xr = gx[j * B_ + b], xz = gx[(j + DEC_) * B_ + b], xn = gx[(j + 2 * DEC_) * B_ + b];
    float hr = gh[j * B_ + b], hz = gh[(j + DEC_) * B_ + b], hnn = gh[(j + 2 * DEC_) * B_ + b];
    float r = 1.f / (1.f + __expf(-(xr + hr)));
    float z = 1.f / (1.f + __expf(-(xz + hz)));
    float n = tanhf(xn + r * hnn);
    float h = (1.f - z) * n + z * h1[b * DEC_ + j];
    hn[b * DEC_ + j] = h;
    hwb[(size_t)b * KHWP_ + j] = f2bf(h);
    outh[b * DEC_ + j] = h;
    pp = h * W_p[j];
  }
  red[threadIdx.x] = pp;
  __syncthreads();
  for (int st = 128; st > 0; st >>= 1) {
    if (threadIdx.x < st) red[threadIdx.x] += red[threadIdx.x + st];
    __syncthreads();
  }
  if (threadIdx.x == 0) atomicAdd(pg_acc + b, red[0]);
}

// logits = hwb . W_out^T + b_out via MFMA; per-tile (max, sumexp) partials.
// r12: double-buffered LDS (2 x 128x96 bf16 = 49152 B, 3 blocks/CU) with ONE
// barrier per chunk: A(c+1) gload_lds + B(c+1) register loads issued right after
// the barrier, flying across the full compute(c) phase, drained exactly at the
// next barrier. Per-row rot3+xor2 permutation (64B-block rotated by row%3,
// 16B slot XOR row&3) applied on the pre-permuted gload SOURCE and the matching
// ds_read offset (both-sides rule) keeps read conflicts ~2-3 way on 192B rows.
__global__ __launch_bounds__(256) void k_outproj(const short* __restrict__ A,
                                                 const float* __restrict__ Wo,
                                                 const float* __restrict__ bo,
                                                 float* __restrict__ out,
                                                 float* __restrict__ pml) {
  __shared__ __align__(16) short A_lds[2 * B_ * CHK_];  // 49152 B
  int tid = threadIdx.x;
  int wave = tid >> 6, lane = tid & 63;
  int r16 = lane & 15, kg = lane >> 4;
  int vcol = blockIdx.x * 64 + wave * 16 + r16;
  int vload = vcol < VOCAB_ ? vcol : VOCAB_ - 1;
  const float* brow = Wo + (size_t)vload * KHW_ + kg * 8;
  f32x4 acc[8];
  #pragma unroll
  for (int mi = 0; mi < 8; ++mi) acc[mi] = (f32x4){0.f, 0.f, 0.f, 0.f};

  // Pre-permuted per-granule source offsets. Granule g = tid + i*256 (16B each),
  // LDS dest byte D = g*16 (linear): row = D/192, p = D%192. Physical slot p holds
  // logical offset l = invP(p): blk_l = (blk_p - row) mod 3, slot_l = slot_p ^ (row&3).
  const char* A8 = (const char*)A;
  uint32_t srcoff[6];
  #pragma unroll
  for (int i = 0; i < 6; ++i) {
    int g = tid + i * 256;
    int row = g / 12, j = g % 12;          // 12 granules per 192B row
    int bp = j >> 2, tp = j & 3;
    int bl = (bp + 3 - row % 3) % 3;
    int tl_ = tp ^ (row & 3);
    srcoff[i] = (uint32_t)(row * 2688 + bl * 64 + tl_ * 16);  // 2688 = KHWP*2
  }
  // Read-side permutation constants: blk = ((s+mi)%3 + r16%3)%3, slot = kg^(r16&3)
  int rm3 = r16 % 3;
  int rot0 = rm3 * 64;
  int rot1 = ((rm3 + 1) % 3) * 64;
  int rot2 = ((rm3 + 2) % 3) * 64;
  int slotoff = (kg ^ (r16 & 3)) << 4;

  float4 br[2][6];   // B double-buffer: 3 k-steps x 2 float4 per chunk
  float  tl[8];      // masked tail (k0=1312) scalars

  // prologue: A(0)->buf0, B(0)->br[0]
  #pragma unroll
  for (int i = 0; i < 6; ++i)
    __builtin_amdgcn_global_load_lds(
        (const __attribute__((address_space(1))) void*)(A8 + srcoff[i]),
        (__attribute__((address_space(3))) void*)((char*)A_lds + i * 4096 + wave * 1024),
        16, 0, 0);
  #pragma unroll
  for (int s = 0; s < 3; ++s) {
    br[0][2 * s]     = *(const float4*)(brow + s * 32);
    br[0][2 * s + 1] = *(const float4*)(brow + s * 32 + 4);
  }

  #pragma unroll
  for (int c = 0; c < NC_; ++c) {
    __syncthreads();  // A(c)+B(c) drained; buf[(c+1)&1]'s old readers done
    if (c < NC_ - 1) {
      char* dstb = (char*)A_lds + ((c + 1) & 1) * 24576;
      #pragma unroll
      for (int i = 0; i < 6; ++i)
        __builtin_amdgcn_global_load_lds(
            (const __attribute__((address_space(1))) void*)(A8 + srcoff[i] + (c + 1) * CHKB_),
            (__attribute__((address_space(3))) void*)(dstb + i * 4096 + wave * 1024),
            16, 0, 0);
      if (c + 1 < NC_ - 1) {
        #pragma unroll
        for (int s = 0; s < 3; ++s) {
          br[(c + 1) & 1][2 * s]     = *(const float4*)(brow + (c + 1) * CHK_ + s * 32);
          br[(c + 1) & 1][2 * s + 1] = *(const float4*)(brow + (c + 1) * CHK_ + s * 32 + 4);
        }
      } else {  // c+1 == 13: steps 0,1 full; step 2 (k0=1312) masked, no OOB
        #pragma unroll
        for (int s = 0; s < 2; ++s) {
          br[(c + 1) & 1][2 * s]     = *(const float4*)(brow + 13 * CHK_ + s * 32);
          br[(c + 1) & 1][2 * s + 1] = *(const float4*)(brow + 13 * CHK_ + s * 32 + 4);
        }
        #pragma unroll
        for (int j = 0; j < 8; ++j)
          tl[j] = (kg * 8 + j < KHW_ - 1312) ? brow[1312 + j] : 0.f;
      }
    }
    // compute chunk c: br[c&1] loaded a full chunk ago; permuted ds_read + MFMA
    const char* rbase = (const char*)A_lds + (c & 1) * 24576 + r16 * CHKB_;
    #pragma unroll
    for (int s = 0; s < 3; ++s) {
      short8 bf;
      if (c == NC_ - 1 && s == 2) {
        #pragma unroll
        for (int j = 0; j < 8; ++j) bf[j] = f2bf(tl[j]);
      } else {
        float4 b0 = br[c & 1][2 * s], b1 = br[c & 1][2 * s + 1];
        bf[0] = f2bf(b0.x); bf[1] = f2bf(b0.y); bf[2] = f2bf(b0.z); bf[3] = f2bf(b0.w);
        bf[4] = f2bf(b1.x); bf[5] = f2bf(b1.y); bf[6] = f2bf(b1.z); bf[7] = f2bf(b1.w);
      }
      #pragma unroll
      for (int mi = 0; mi < 8; ++mi) {
        int t = (s + mi) % 3;  // compile-time under full unroll
        int blkoff = (t == 0) ? rot0 : ((t == 1) ? rot1 : rot2);
        short8 af = *(const short8*)(rbase + mi * 3072 + blkoff + slotoff);
        acc[mi] = __builtin_amdgcn_mfma_f32_16x16x32_bf16(af, bf, acc[mi], 0, 0, 0);
      }
    }
  }

  __syncthreads();  // drain all LDS reads; staging dead -> reuse for stats
  float* wml = (float*)A_lds;  // [4][B_][2] floats = 4096 B

  bool valid = vcol < VOCAB_;
  float biasv = bo[vload];
  #pragma unroll
  for (int mi = 0; mi < 8; ++mi) {
    #pragma unroll
    for (int j = 0; j < 4; ++j) {
      float lv = valid ? acc[mi][j] + biasv : -INFINITY;
      if (valid) out[(size_t)(mi * 16 + kg * 4 + j) * OUTW_ + vcol] = lv;
      float mr = lv;
      #pragma unroll
      for (int msk = 1; msk < 16; msk <<= 1) mr = fmaxf(mr, __shfl_xor(mr, msk));
      float se = valid ? __expf(lv - mr) : 0.f;
      #pragma unroll
      for (int msk = 1; msk < 16; msk <<= 1) se += __shfl_xor(se, msk);
      if (r16 == 0) {
        wml[(wave * B_ + mi * 16 + kg * 4 + j) * 2]     = mr;
        wml[(wave * B_ + mi * 16 + kg * 4 + j) * 2 + 1] = se;
      }
    }
  }
  __syncthreads();
  if (tid < B_) {
    float M = -INFINITY;
    #pragma unroll
    for (int w = 0; w < 4; ++w) M = fmaxf(M, wml[(w * B_ + tid) * 2]);
    float L = 0.f;
    #pragma unroll
    for (int w = 0; w < 4; ++w) {
      float lw = wml[(w * B_ + tid) * 2 + 1];
      if (lw > 0.f) L += lw * __expf(wml[(w * B_ + tid) * 2] - M);
    }
    pml[((size_t)blockIdx.x * B_ + tid) * 2]     = M;
    pml[((size_t)blockIdx.x * B_ + tid) * 2 + 1] = L;
  }
}

// Merge tile partials -> global (M,L); scale vocab region; zero OOV. 4 blocks per b.
__global__ __launch_bounds__(256) void k_vfinal(float* __restrict__ out,
                                                const float* __restrict__ pml,
                                                const float* __restrict__ pg,
                                                float* __restrict__ mlv) {
  int bq = blockIdx.x, b = blockIdx.y, t = threadIdx.x;
  __shared__ float rm[256], rl[256];
  float lm = -INFINITY, ll = 0.f;
  for (int tile = t; tile < NTILE_; tile += 256) {
    float m = pml[((size_t)tile * B_ + b) * 2];
    float l = pml[((size_t)tile * B_ + b) * 2 + 1];
    float M = fmaxf(lm, m);
    float nl = 0.f;
    if (ll > 0.f) nl += ll * __expf(lm - M);
    if (l > 0.f) nl += l * __expf(m - M);
    lm = M; ll = nl;
  }
  rm[t] = lm; rl[t] = ll;
  __syncthreads();
  for (int st = 128; st > 0; st >>= 1) {
    if (t < st) {
      float m1 = rm[t], l1 = rl[t], m2 = rm[t + st], l2 = rl[t + st];
      float M = fmaxf(m1, m2);
      float L = (l1 > 0.f ? l1 * __expf(m1 - M) : 0.f) + (l2 > 0.f ? l2 * __expf(m2 - M) : 0.f);
      rm[t] = M; rl[t] = L;
    }
    __syncthreads();
  }
  float M = rm[0], L = rl[0];
  float scale = pg[b] / L;
  float* row = out + (size_t)b * OUTW_;
  int lo = bq * 12513;
  int hi = min(lo + 12513, OUTW_);
  for (int v = lo + t; v < hi; v += 256)
    row[v] = (v < VOCAB_) ? scale * __expf(row[v] - M) : 0.f;
  if (bq == 0 && t == 0) { mlv[b * 2] = M; mlv[b * 2 + 1] = L; }
}

// Copy-mechanism scatter (after vfinal): p_out[b, src] += (1-pg)*a2
__global__ __launch_bounds__(256) void k_scatter2(float* __restrict__ out,
                                                  const int* __restrict__ src,
                                                  const float* __restrict__ scores,
                                                  const float* __restrict__ ml2,
                                                  const float* __restrict__ pg) {
  int b = blockIdx.x, t = threadIdx.x;
  float M2 = ml2[b * 2], L2 = ml2[b * 2 + 1];
  float q = (1.f - pg[b]) / L2;
  float* row = out + (size_t)b * OUTW_;
  for (int s = t; s < S_; s += 256) {
    float val = q * __expf(scores[b * S_ + s] - M2);
    atomicAdd(row + src[b * S_ + s], val);
  }
}

extern "C" void kernel_launch(void* const* d_in, const int* in_sizes, int n_in,
                              void* d_out, int out_size, void* d_ws, size_t ws_size,
                              hipStream_t stream) {
  const float* embedded = (const float*)d_in[0];
  const float* enc      = (const float*)d_in[1];
  const float* h1       = (const float*)d_in[2];
  const int*   src      = (const int*)d_in[5];
  const float* W1       = (const float*)d_in[6];
  const float* W2       = (const float*)d_in[7];
  const float* W_ih     = (const float*)d_in[8];
  const float* W_hh     = (const float*)d_in[9];
  const float* b_ih     = (const float*)d_in[10];
  const float* b_hh     = (const float*)d_in[11];
  const float* W_out    = (const float*)d_in[12];
  const float* b_out    = (const float*)d_in[13];
  const float* W_p      = (const float*)d_in[14];
  const float* b_p      = (const float*)d_in[15];
  float* out = (float*)d_out;
  float* ws  = (float*)d_ws;

  // Workspace (cumulative, no overlaps; ~21 MB total, ws is ~1 GB)
  size_t off = 0;
  float* v_ws    = ws + off; off += (size_t)B_ * ENC_;      // 131072
  float* w1_ws   = ws + off; off += (size_t)B_ * ENC_;      // 131072
  float* gx_ws   = ws + off; off += (size_t)G3_ * B_;       // 115200
  float* gh_ws   = ws + off; off += (size_t)G3_ * B_;       // 115200
  float* hn_ws   = ws + off; off += (size_t)B_ * DEC_;      // 38400
  float* sc_ws   = ws + off; off += (size_t)B_ * S_;        // 51200
  float* ml2_ws  = ws + off; off += 256;
  float* pg_ws   = ws + off; off += 128;
  float* pga_ws  = ws + off; off += 128;
  float* mlv_ws  = ws + off; off += 256;
  float* pml_ws  = ws + off; off += (size_t)NTILE_ * B_ * 2; // 200192
  short* hwb_ws  = (short*)(ws + off); off += (size_t)B_ * KHWP_ / 2;  // 86016
  float* part_ws = ws + off;                                 // B*NS*4*PSTRIDE

  int NS = 8;
  while (NS > 1 && (off + (size_t)B_ * NS * 4 * PSTRIDE_) * 4 > ws_size) NS >>= 1;

  // attention 1 -> w1 (flash, one enc sweep)
  k_compute_v<<<B_, 256, 0, stream>>>(W1, h1, v_ws);
  k_attn_pass<<<dim3(B_, NS), 256, 0, stream>>>(enc, v_ws, sc_ws, part_ws, NS);
  k_attn_merge1<<<B_, 256, 0, stream>>>(part_ws, NS * 4, w1_ws);
  // GRU -> h_new (hn f32; hwb bf16 h-part; d_out tail; pg h-partial)
  k_gates<<<(G3_ * B_) / 256, 256, 0, stream>>>(embedded, w1_ws, h1, W_ih, W_hh, b_ih, b_hh,
                                                gx_ws, gh_ws, pga_ws);
  k_gru_combine<<<dim3(2, B_), 256, 0, stream>>>(gx_ws, gh_ws, h1, hn_ws, hwb_ws,
                                                 out + (size_t)B_ * OUTW_, W_p, pga_ws);
  // attention 2 -> hwb w2-part, ml2, p_gen finished
  k_compute_v<<<B_, 256, 0, stream>>>(W2, hn_ws, v_ws);
  k_attn_pass<<<dim3(B_, NS), 256, 0, stream>>>(enc, v_ws, sc_ws, part_ws, NS);
  k_attn_merge2<<<B_, 256, 0, stream>>>(part_ws, NS * 4, hwb_ws, ml2_ws, W_p, b_p,
                                        pga_ws, pg_ws);
  // vocab projection (+ per-tile softmax partials), merge+scale, scatter
  k_outproj<<<NTILE_, 256, 0, stream>>>(hwb_ws, W_out, b_out, out, pml_ws);
  k_vfinal<<<dim3(4, B_), 256, 0, stream>>>(out, pml_ws, pg_ws, mlv_ws);
  k_scatter2<<<B_, 256, 0, stream>>>(out, src, sc_ws, ml2_ws, pg_ws);
}